// Round 1
// baseline (9264.009 us; speedup 1.0000x reference)
//
#include <hip/hip_runtime.h>
#include <hip/hip_bf16.h>

#define N_NODES 100000
#define E_EDGES 1600000
#define IN_DIM  256
#define HID     128
#define OUT_DIM 64
#define LAYERS  3
#define LN_EPS  1e-5f

// ---------------- degree / dinv ----------------

__global__ __launch_bounds__(256) void deg_kernel(const int* __restrict__ dst, int* __restrict__ deg) {
    int e = blockIdx.x * 256 + threadIdx.x;
    if (e < E_EDGES) atomicAdd(&deg[dst[e]], 1);
}

__global__ __launch_bounds__(256) void dinv_kernel(const int* __restrict__ deg, float* __restrict__ dinv) {
    int i = blockIdx.x * 256 + threadIdx.x;
    if (i < N_NODES) dinv[i] = rsqrtf((float)(deg[i] + 1));  // +1 = self loop
}

// ---------------- tiled f32 GEMM: C[M,BN] = A[M,K] @ W[K,BN] (+bias) ----------------
// BM=64 rows per block, full N resident in LDS per BK=32 chunk.

template<int K, int BN>
__global__ __launch_bounds__(256) void gemm_kernel(const float* __restrict__ A,
                                                   const float* __restrict__ W,
                                                   const float* __restrict__ bias,
                                                   float* __restrict__ C, int M) {
    constexpr int BM = 64;
    constexpr int BK = 32;
    constexpr int TX = BN / 4;        // threads along cols (each owns 4 cols)
    constexpr int TY = 256 / TX;      // threads along rows
    constexpr int RPT = BM / TY;      // rows per thread

    __shared__ float As[BM][BK + 1];
    __shared__ float Ws[BK][BN];

    const int tid = threadIdx.x;
    const int tx = tid % TX;
    const int ty = tid / TX;
    const int row0 = blockIdx.x * BM;

    float4 acc[RPT];
#pragma unroll
    for (int j = 0; j < RPT; j++) acc[j] = make_float4(0.f, 0.f, 0.f, 0.f);

    for (int k0 = 0; k0 < K; k0 += BK) {
        // A tile: 64x32 floats, 8 per thread, coalesced along k
        {
            int lk = tid % BK;
            int lr = tid / BK;            // 0..7
#pragma unroll
            for (int j = 0; j < BM / 8; j++) {
                int r = lr + j * 8;
                int gr = row0 + r;
                As[r][lk] = (gr < M) ? A[(long)gr * K + k0 + lk] : 0.0f;
            }
        }
        // W tile: BKxBN floats, coalesced
        {
            constexpr int TOT = BK * BN;
#pragma unroll
            for (int idx = tid; idx < TOT; idx += 256) {
                int kk = idx / BN, cc = idx % BN;
                Ws[kk][cc] = W[(long)(k0 + kk) * BN + cc];
            }
        }
        __syncthreads();
#pragma unroll
        for (int kk = 0; kk < BK; kk++) {
            float4 w4 = *reinterpret_cast<const float4*>(&Ws[kk][tx * 4]);
#pragma unroll
            for (int j = 0; j < RPT; j++) {
                float a = As[ty + j * TY][kk];
                acc[j].x += a * w4.x;
                acc[j].y += a * w4.y;
                acc[j].z += a * w4.z;
                acc[j].w += a * w4.w;
            }
        }
        __syncthreads();
    }

    float4 b4 = make_float4(0.f, 0.f, 0.f, 0.f);
    if (bias) b4 = *reinterpret_cast<const float4*>(&bias[tx * 4]);
#pragma unroll
    for (int j = 0; j < RPT; j++) {
        int r = row0 + ty + j * TY;
        if (r < M) {
            float4 o = make_float4(acc[j].x + b4.x, acc[j].y + b4.y,
                                   acc[j].z + b4.z, acc[j].w + b4.w);
            *reinterpret_cast<float4*>(&C[(long)r * BN + tx * 4]) = o;
        }
    }
}

// ---------------- edge scatter: agg[dst] += xw[src] * dinv[src]*dinv[dst] ----------------
// 32 lanes per edge, float4 per lane (128 features).

__global__ __launch_bounds__(256) void scatter_kernel(const int* __restrict__ src,
                                                      const int* __restrict__ dst,
                                                      const float* __restrict__ dinv,
                                                      const float* __restrict__ xw,
                                                      float* __restrict__ agg) {
    long t = (long)blockIdx.x * 256 + threadIdx.x;
    long e = t >> 5;
    int lane = (int)(t & 31);
    if (e >= E_EDGES) return;
    int s = src[e], d = dst[e];
    float w = dinv[s] * dinv[d];
    float4 v = *reinterpret_cast<const float4*>(&xw[(long)s * HID + lane * 4]);
    float* p = &agg[(long)d * HID + lane * 4];
    unsafeAtomicAdd(p + 0, v.x * w);
    unsafeAtomicAdd(p + 1, v.y * w);
    unsafeAtomicAdd(p + 2, v.z * w);
    unsafeAtomicAdd(p + 3, v.w * w);
}

// ---------------- post: y = LN(agg + selfloop + b)*g + beta; relu; h += y ----------------
// one wave (64 lanes) per row, 2 floats per lane.

__global__ __launch_bounds__(256) void post_kernel(const float* __restrict__ agg,
                                                   const float* __restrict__ xw,
                                                   const float* __restrict__ dinv,
                                                   const float* __restrict__ b,
                                                   const float* __restrict__ g,
                                                   const float* __restrict__ beta,
                                                   float* __restrict__ h) {
    int wave = threadIdx.x >> 6;
    int lane = threadIdx.x & 63;
    int row = blockIdx.x * 4 + wave;
    if (row >= N_NODES) return;

    float di = dinv[row];
    float selfw = di * di;

    float2 av = *reinterpret_cast<const float2*>(&agg[(long)row * HID + lane * 2]);
    float2 xv = *reinterpret_cast<const float2*>(&xw[(long)row * HID + lane * 2]);
    float2 bv = *reinterpret_cast<const float2*>(&b[lane * 2]);
    float y0 = av.x + xv.x * selfw + bv.x;
    float y1 = av.y + xv.y * selfw + bv.y;

    float sum = y0 + y1;
#pragma unroll
    for (int off = 32; off; off >>= 1) sum += __shfl_xor(sum, off);
    float mu = sum * (1.0f / HID);

    float d0 = y0 - mu, d1 = y1 - mu;
    float vs = d0 * d0 + d1 * d1;
#pragma unroll
    for (int off = 32; off; off >>= 1) vs += __shfl_xor(vs, off);
    float rstd = rsqrtf(vs * (1.0f / HID) + LN_EPS);

    float2 gv = *reinterpret_cast<const float2*>(&g[lane * 2]);
    float2 bev = *reinterpret_cast<const float2*>(&beta[lane * 2]);
    float r0 = fmaxf(d0 * rstd * gv.x + bev.x, 0.0f);
    float r1 = fmaxf(d1 * rstd * gv.y + bev.y, 0.0f);

    float2* hp = reinterpret_cast<float2*>(&h[(long)row * HID + lane * 2]);
    float2 hv = *hp;
    hv.x += r0;
    hv.y += r1;
    *hp = hv;
}

// ---------------- launch ----------------

extern "C" void kernel_launch(void* const* d_in, const int* in_sizes, int n_in,
                              void* d_out, int out_size, void* d_ws, size_t ws_size,
                              hipStream_t stream) {
    const float* x      = (const float*)d_in[0];
    const int*   eidx   = (const int*)d_in[1];
    const float* in_W   = (const float*)d_in[2];
    const float* in_b   = (const float*)d_in[3];
    const float* conv_W = (const float*)d_in[4];
    const float* conv_b = (const float*)d_in[5];
    const float* ln_g   = (const float*)d_in[6];
    const float* ln_b   = (const float*)d_in[7];
    const float* out_W  = (const float*)d_in[8];
    const float* out_b  = (const float*)d_in[9];

    const int* src = eidx;
    const int* dst = eidx + E_EDGES;

    char* ws = (char*)d_ws;
    size_t off = 0;
    auto alloc = [&](size_t bytes) {
        void* p = ws + off;
        off += (bytes + 1023) & ~(size_t)1023;
        return p;
    };
    int*   deg  = (int*)  alloc((size_t)N_NODES * 4);
    float* dinv = (float*)alloc((size_t)N_NODES * 4);
    float* h    = (float*)alloc((size_t)N_NODES * HID * 4);
    float* xw   = (float*)alloc((size_t)N_NODES * HID * 4);
    float* agg  = (float*)alloc((size_t)N_NODES * HID * 4);

    hipMemsetAsync(deg, 0, (size_t)N_NODES * 4, stream);
    deg_kernel<<<(E_EDGES + 255) / 256, 256, 0, stream>>>(dst, deg);
    dinv_kernel<<<(N_NODES + 255) / 256, 256, 0, stream>>>(deg, dinv);

    gemm_kernel<IN_DIM, HID><<<(N_NODES + 63) / 64, 256, 0, stream>>>(x, in_W, in_b, h, N_NODES);

    for (int l = 0; l < LAYERS; l++) {
        gemm_kernel<HID, HID><<<(N_NODES + 63) / 64, 256, 0, stream>>>(
            h, conv_W + (size_t)l * HID * HID, nullptr, xw, N_NODES);
        hipMemsetAsync(agg, 0, (size_t)N_NODES * HID * 4, stream);
        scatter_kernel<<<(int)(((long)E_EDGES * 32 + 255) / 256), 256, 0, stream>>>(
            src, dst, dinv, xw, agg);
        post_kernel<<<(N_NODES + 3) / 4, 256, 0, stream>>>(
            agg, xw, dinv, conv_b + l * HID, ln_g + l * HID, ln_b + l * HID, h);
    }

    gemm_kernel<HID, OUT_DIM><<<(N_NODES + 63) / 64, 256, 0, stream>>>(
        h, out_W, out_b, (float*)d_out, N_NODES);
}

// Round 2
// 1625.527 us; speedup vs baseline: 5.6991x; 5.6991x over previous
//
#include <hip/hip_runtime.h>
#include <hip/hip_bf16.h>

#define N_NODES 100000
#define E_EDGES 1600000
#define IN_DIM  256
#define HID     128
#define OUT_DIM 64
#define LAYERS  3
#define LN_EPS  1e-5f

// ---------------- degree / dinv ----------------

__global__ __launch_bounds__(256) void deg_kernel(const int* __restrict__ dst, int* __restrict__ deg) {
    int e = blockIdx.x * 256 + threadIdx.x;
    if (e < E_EDGES) atomicAdd(&deg[dst[e]], 1);
}

__global__ __launch_bounds__(256) void dinv_kernel(const int* __restrict__ deg, float* __restrict__ dinv) {
    int i = blockIdx.x * 256 + threadIdx.x;
    if (i < N_NODES) dinv[i] = rsqrtf((float)(deg[i] + 1));  // +1 = self loop
}

// ---------------- CSR build: exclusive scan of deg ----------------

#define NB_SCAN ((N_NODES + 255) / 256)   // 391

__global__ __launch_bounds__(256) void block_sum_kernel(const int* __restrict__ deg,
                                                        int* __restrict__ blockSums) {
    __shared__ int s[256];
    int i = blockIdx.x * 256 + threadIdx.x;
    s[threadIdx.x] = (i < N_NODES) ? deg[i] : 0;
    __syncthreads();
#pragma unroll
    for (int o = 128; o; o >>= 1) {
        if (threadIdx.x < o) s[threadIdx.x] += s[threadIdx.x + o];
        __syncthreads();
    }
    if (threadIdx.x == 0) blockSums[blockIdx.x] = s[0];
}

__global__ __launch_bounds__(512) void scan_blocks_kernel(int* __restrict__ blockSums, int nb) {
    __shared__ int s[512];
    int t = threadIdx.x;
    int orig = (t < nb) ? blockSums[t] : 0;
    s[t] = orig;
    __syncthreads();
#pragma unroll
    for (int o = 1; o < 512; o <<= 1) {
        int v = (t >= o) ? s[t - o] : 0;
        __syncthreads();
        s[t] += v;
        __syncthreads();
    }
    if (t < nb) blockSums[t] = s[t] - orig;   // exclusive
}

__global__ __launch_bounds__(256) void scan_final_kernel(const int* __restrict__ deg,
                                                         const int* __restrict__ blockSums,
                                                         int* __restrict__ offsets,
                                                         int* __restrict__ cursor) {
    __shared__ int s[256];
    int i = blockIdx.x * 256 + threadIdx.x;
    int t = threadIdx.x;
    int v = (i < N_NODES) ? deg[i] : 0;
    s[t] = v;
    __syncthreads();
#pragma unroll
    for (int o = 1; o < 256; o <<= 1) {
        int u = (t >= o) ? s[t - o] : 0;
        __syncthreads();
        s[t] += u;
        __syncthreads();
    }
    if (i < N_NODES) {
        int excl = s[t] - v + blockSums[blockIdx.x];
        offsets[i] = excl;
        cursor[i] = excl;
    }
}

__global__ __launch_bounds__(256) void bin_kernel(const int* __restrict__ src,
                                                  const int* __restrict__ dst,
                                                  const float* __restrict__ dinv,
                                                  int* __restrict__ cursor,
                                                  int* __restrict__ src_sorted,
                                                  float* __restrict__ w_sorted) {
    int e = blockIdx.x * 256 + threadIdx.x;
    if (e >= E_EDGES) return;
    int s = src[e], d = dst[e];
    int p = atomicAdd(&cursor[d], 1);
    src_sorted[p] = s;
    w_sorted[p] = dinv[s] * dinv[d];
}

// ---------------- tiled f32 GEMM: C[M,BN] = A[M,K] @ W[K,BN] (+bias) ----------------

template<int K, int BN>
__global__ __launch_bounds__(256) void gemm_kernel(const float* __restrict__ A,
                                                   const float* __restrict__ W,
                                                   const float* __restrict__ bias,
                                                   float* __restrict__ C, int M) {
    constexpr int BM = 64;
    constexpr int BK = 32;
    constexpr int TX = BN / 4;
    constexpr int TY = 256 / TX;
    constexpr int RPT = BM / TY;

    __shared__ float As[BM][BK + 1];
    __shared__ float Ws[BK][BN];

    const int tid = threadIdx.x;
    const int tx = tid % TX;
    const int ty = tid / TX;
    const int row0 = blockIdx.x * BM;

    float4 acc[RPT];
#pragma unroll
    for (int j = 0; j < RPT; j++) acc[j] = make_float4(0.f, 0.f, 0.f, 0.f);

    for (int k0 = 0; k0 < K; k0 += BK) {
        {
            int lk = tid % BK;
            int lr = tid / BK;
#pragma unroll
            for (int j = 0; j < BM / 8; j++) {
                int r = lr + j * 8;
                int gr = row0 + r;
                As[r][lk] = (gr < M) ? A[(long)gr * K + k0 + lk] : 0.0f;
            }
        }
        {
            constexpr int TOT = BK * BN;
#pragma unroll
            for (int idx = tid; idx < TOT; idx += 256) {
                int kk = idx / BN, cc = idx % BN;
                Ws[kk][cc] = W[(long)(k0 + kk) * BN + cc];
            }
        }
        __syncthreads();
#pragma unroll
        for (int kk = 0; kk < BK; kk++) {
            float4 w4 = *reinterpret_cast<const float4*>(&Ws[kk][tx * 4]);
#pragma unroll
            for (int j = 0; j < RPT; j++) {
                float a = As[ty + j * TY][kk];
                acc[j].x += a * w4.x;
                acc[j].y += a * w4.y;
                acc[j].z += a * w4.z;
                acc[j].w += a * w4.w;
            }
        }
        __syncthreads();
    }

    float4 b4 = make_float4(0.f, 0.f, 0.f, 0.f);
    if (bias) b4 = *reinterpret_cast<const float4*>(&bias[tx * 4]);
#pragma unroll
    for (int j = 0; j < RPT; j++) {
        int r = row0 + ty + j * TY;
        if (r < M) {
            float4 o = make_float4(acc[j].x + b4.x, acc[j].y + b4.y,
                                   acc[j].z + b4.z, acc[j].w + b4.w);
            *reinterpret_cast<float4*>(&C[(long)r * BN + tx * 4]) = o;
        }
    }
}

// ---------------- fused gather + selfloop + bias + LN + relu + residual ----------------
// one wave (64 lanes) per node, 2 floats per lane.

__global__ __launch_bounds__(256) void gather_post_kernel(const int* __restrict__ offsets,
                                                          const int* __restrict__ deg,
                                                          const int* __restrict__ src_sorted,
                                                          const float* __restrict__ w_sorted,
                                                          const float* __restrict__ dinv,
                                                          const float* __restrict__ xw,
                                                          const float* __restrict__ b,
                                                          const float* __restrict__ g,
                                                          const float* __restrict__ beta,
                                                          float* __restrict__ h) {
    int wave = threadIdx.x >> 6;
    int lane = threadIdx.x & 63;
    int row = blockIdx.x * 4 + wave;
    if (row >= N_NODES) return;

    int off = offsets[row];
    int dg = deg[row];

    float acc0 = 0.f, acc1 = 0.f;
    int j = 0;
    for (; j + 4 <= dg; j += 4) {
        int s0 = src_sorted[off + j + 0];
        int s1 = src_sorted[off + j + 1];
        int s2 = src_sorted[off + j + 2];
        int s3 = src_sorted[off + j + 3];
        float w0 = w_sorted[off + j + 0];
        float w1 = w_sorted[off + j + 1];
        float w2 = w_sorted[off + j + 2];
        float w3 = w_sorted[off + j + 3];
        float2 v0 = *reinterpret_cast<const float2*>(&xw[(long)s0 * HID + lane * 2]);
        float2 v1 = *reinterpret_cast<const float2*>(&xw[(long)s1 * HID + lane * 2]);
        float2 v2 = *reinterpret_cast<const float2*>(&xw[(long)s2 * HID + lane * 2]);
        float2 v3 = *reinterpret_cast<const float2*>(&xw[(long)s3 * HID + lane * 2]);
        acc0 += v0.x * w0; acc1 += v0.y * w0;
        acc0 += v1.x * w1; acc1 += v1.y * w1;
        acc0 += v2.x * w2; acc1 += v2.y * w2;
        acc0 += v3.x * w3; acc1 += v3.y * w3;
    }
    for (; j < dg; j++) {
        int s0 = src_sorted[off + j];
        float w0 = w_sorted[off + j];
        float2 v0 = *reinterpret_cast<const float2*>(&xw[(long)s0 * HID + lane * 2]);
        acc0 += v0.x * w0; acc1 += v0.y * w0;
    }

    // self loop + bias
    float di = dinv[row];
    float sw = di * di;
    float2 xv = *reinterpret_cast<const float2*>(&xw[(long)row * HID + lane * 2]);
    float2 bv = *reinterpret_cast<const float2*>(&b[lane * 2]);
    float y0 = acc0 + xv.x * sw + bv.x;
    float y1 = acc1 + xv.y * sw + bv.y;

    // LayerNorm over 128 features (64 lanes x 2)
    float sum = y0 + y1;
#pragma unroll
    for (int o = 32; o; o >>= 1) sum += __shfl_xor(sum, o);
    float mu = sum * (1.0f / HID);

    float d0 = y0 - mu, d1 = y1 - mu;
    float vs = d0 * d0 + d1 * d1;
#pragma unroll
    for (int o = 32; o; o >>= 1) vs += __shfl_xor(vs, o);
    float rstd = rsqrtf(vs * (1.0f / HID) + LN_EPS);

    float2 gv = *reinterpret_cast<const float2*>(&g[lane * 2]);
    float2 bev = *reinterpret_cast<const float2*>(&beta[lane * 2]);
    float r0 = fmaxf(d0 * rstd * gv.x + bev.x, 0.0f);
    float r1 = fmaxf(d1 * rstd * gv.y + bev.y, 0.0f);

    float2* hp = reinterpret_cast<float2*>(&h[(long)row * HID + lane * 2]);
    float2 hv = *hp;
    hv.x += r0;
    hv.y += r1;
    *hp = hv;
}

// ---------------- launch ----------------

extern "C" void kernel_launch(void* const* d_in, const int* in_sizes, int n_in,
                              void* d_out, int out_size, void* d_ws, size_t ws_size,
                              hipStream_t stream) {
    const float* x      = (const float*)d_in[0];
    const int*   eidx   = (const int*)d_in[1];
    const float* in_W   = (const float*)d_in[2];
    const float* in_b   = (const float*)d_in[3];
    const float* conv_W = (const float*)d_in[4];
    const float* conv_b = (const float*)d_in[5];
    const float* ln_g   = (const float*)d_in[6];
    const float* ln_b   = (const float*)d_in[7];
    const float* out_W  = (const float*)d_in[8];
    const float* out_b  = (const float*)d_in[9];

    const int* src = eidx;
    const int* dst = eidx + E_EDGES;

    char* ws = (char*)d_ws;
    size_t off = 0;
    auto alloc = [&](size_t bytes) {
        void* p = ws + off;
        off += (bytes + 1023) & ~(size_t)1023;
        return p;
    };
    int*   deg        = (int*)  alloc((size_t)N_NODES * 4);
    float* dinv       = (float*)alloc((size_t)N_NODES * 4);
    int*   offsets    = (int*)  alloc((size_t)N_NODES * 4);
    int*   cursor     = (int*)  alloc((size_t)N_NODES * 4);
    int*   blockSums  = (int*)  alloc((size_t)NB_SCAN * 4);
    int*   src_sorted = (int*)  alloc((size_t)E_EDGES * 4);
    float* w_sorted   = (float*)alloc((size_t)E_EDGES * 4);
    float* h          = (float*)alloc((size_t)N_NODES * HID * 4);
    float* xw         = (float*)alloc((size_t)N_NODES * HID * 4);

    hipMemsetAsync(deg, 0, (size_t)N_NODES * 4, stream);
    deg_kernel<<<(E_EDGES + 255) / 256, 256, 0, stream>>>(dst, deg);
    dinv_kernel<<<(N_NODES + 255) / 256, 256, 0, stream>>>(deg, dinv);

    // CSR build
    block_sum_kernel<<<NB_SCAN, 256, 0, stream>>>(deg, blockSums);
    scan_blocks_kernel<<<1, 512, 0, stream>>>(blockSums, NB_SCAN);
    scan_final_kernel<<<NB_SCAN, 256, 0, stream>>>(deg, blockSums, offsets, cursor);
    bin_kernel<<<(E_EDGES + 255) / 256, 256, 0, stream>>>(src, dst, dinv, cursor,
                                                          src_sorted, w_sorted);

    gemm_kernel<IN_DIM, HID><<<(N_NODES + 63) / 64, 256, 0, stream>>>(x, in_W, in_b, h, N_NODES);

    for (int l = 0; l < LAYERS; l++) {
        gemm_kernel<HID, HID><<<(N_NODES + 63) / 64, 256, 0, stream>>>(
            h, conv_W + (size_t)l * HID * HID, nullptr, xw, N_NODES);
        gather_post_kernel<<<(N_NODES + 3) / 4, 256, 0, stream>>>(
            offsets, deg, src_sorted, w_sorted, dinv, xw,
            conv_b + l * HID, ln_g + l * HID, ln_b + l * HID, h);
    }

    gemm_kernel<HID, OUT_DIM><<<(N_NODES + 63) / 64, 256, 0, stream>>>(
        h, out_W, out_b, (float*)d_out, N_NODES);
}

// Round 4
// 1492.366 us; speedup vs baseline: 6.2076x; 1.0892x over previous
//
#include <hip/hip_runtime.h>
#include <hip/hip_bf16.h>

#define N_NODES 100000
#define E_EDGES 1600000
#define IN_DIM  256
#define HID     128
#define OUT_DIM 64
#define LAYERS  3
#define LN_EPS  1e-5f

// ---------------- degree / dinv ----------------

__global__ __launch_bounds__(256) void deg_kernel(const int* __restrict__ dst, int* __restrict__ deg) {
    int e = blockIdx.x * 256 + threadIdx.x;
    if (e < E_EDGES) atomicAdd(&deg[dst[e]], 1);
}

__global__ __launch_bounds__(256) void dinv_kernel(const int* __restrict__ deg, float* __restrict__ dinv) {
    int i = blockIdx.x * 256 + threadIdx.x;
    if (i < N_NODES) dinv[i] = rsqrtf((float)(deg[i] + 1));  // +1 = self loop
}

// ---------------- CSR build: exclusive scan of deg ----------------

#define NB_SCAN ((N_NODES + 255) / 256)   // 391

__global__ __launch_bounds__(256) void block_sum_kernel(const int* __restrict__ deg,
                                                        int* __restrict__ blockSums) {
    __shared__ int s[256];
    int i = blockIdx.x * 256 + threadIdx.x;
    s[threadIdx.x] = (i < N_NODES) ? deg[i] : 0;
    __syncthreads();
#pragma unroll
    for (int o = 128; o; o >>= 1) {
        if (threadIdx.x < o) s[threadIdx.x] += s[threadIdx.x + o];
        __syncthreads();
    }
    if (threadIdx.x == 0) blockSums[blockIdx.x] = s[0];
}

__global__ __launch_bounds__(512) void scan_blocks_kernel(int* __restrict__ blockSums, int nb) {
    __shared__ int s[512];
    int t = threadIdx.x;
    int orig = (t < nb) ? blockSums[t] : 0;
    s[t] = orig;
    __syncthreads();
#pragma unroll
    for (int o = 1; o < 512; o <<= 1) {
        int v = (t >= o) ? s[t - o] : 0;
        __syncthreads();
        s[t] += v;
        __syncthreads();
    }
    if (t < nb) blockSums[t] = s[t] - orig;   // exclusive
}

__global__ __launch_bounds__(256) void scan_final_kernel(const int* __restrict__ deg,
                                                         const int* __restrict__ blockSums,
                                                         int* __restrict__ offsets,
                                                         int* __restrict__ cursor) {
    __shared__ int s[256];
    int i = blockIdx.x * 256 + threadIdx.x;
    int t = threadIdx.x;
    int v = (i < N_NODES) ? deg[i] : 0;
    s[t] = v;
    __syncthreads();
#pragma unroll
    for (int o = 1; o < 256; o <<= 1) {
        int u = (t >= o) ? s[t - o] : 0;
        __syncthreads();
        s[t] += u;
        __syncthreads();
    }
    if (i < N_NODES) {
        int excl = s[t] - v + blockSums[blockIdx.x];
        offsets[i] = excl;
        cursor[i] = excl;
    }
}

__global__ __launch_bounds__(256) void bin_kernel(const int* __restrict__ src,
                                                  const int* __restrict__ dst,
                                                  const float* __restrict__ dinv,
                                                  int* __restrict__ cursor,
                                                  int2* __restrict__ es) {
    int e = blockIdx.x * 256 + threadIdx.x;
    if (e >= E_EDGES) return;
    int s = src[e], d = dst[e];
    int p = atomicAdd(&cursor[d], 1);
    es[p] = make_int2(s, __float_as_int(dinv[s] * dinv[d]));
}

// ---------------- f32 GEMM: C[M,BN] = A[M,K] @ W[K,BN] (+bias) ----------------
// W chunk (BK x BN) LDS-resident; A streamed global->reg, named double buffer,
// NO barriers in the inner loop. Thread tile 8 rows x TN cols.
// Lane layout: rg = tid&15 (rows), tx = tid>>4 (cols) -> W ds_read_b128 is a
// 16-lane broadcast of 4 unique conflict-free addresses.

template<int K, int BN>
__global__ __launch_bounds__(256) void gemm_kernel(const float* __restrict__ A,
                                                   const float* __restrict__ W,
                                                   const float* __restrict__ bias,
                                                   float* __restrict__ C, int M) {
    constexpr int TX = 16;
    constexpr int TN = BN / TX;                    // 8 (BN=128) or 4 (BN=64)
    constexpr int NQ = TN / 4;                     // 2 or 1
    constexpr int TM = 8;
    constexpr int BM = 128;
    constexpr int BK = (8192 / BN) < K ? (8192 / BN) : K;  // 64 or 128 -> LDS 32KB

    __shared__ float Ws[BK * BN];

    const int tid = threadIdx.x;
    const int rg = tid & 15;
    const int tx = tid >> 4;
    const int c0 = tx * TN;
    const int row0 = blockIdx.x * BM;

    const float* arow[TM];
#pragma unroll
    for (int m = 0; m < TM; m++) {
        int r = row0 + rg + 16 * m;
        if (r > M - 1) r = M - 1;                  // clamp; store is guarded
        arow[m] = A + (long)r * K;
    }

    float4 acc[TM][NQ];
#pragma unroll
    for (int m = 0; m < TM; m++)
#pragma unroll
        for (int q = 0; q < NQ; q++) acc[m][q] = make_float4(0.f, 0.f, 0.f, 0.f);

    float4 bufA[TM], bufB[TM];

    auto stage = [&](int k0) {
        const float4* srcp = (const float4*)(W + (long)k0 * BN);
        float4* dstp = (float4*)Ws;
#pragma unroll
        for (int i = 0; i < (BK * BN / 4) / 256; i++)
            dstp[tid + 256 * i] = srcp[tid + 256 * i];
    };

    auto loadA = [&](int kg, float4* b) {
#pragma unroll
        for (int m = 0; m < TM; m++) b[m] = *(const float4*)(arow[m] + kg);
    };

    auto compute = [&](int kl, const float4* b) {
#pragma unroll
        for (int kk = 0; kk < 4; kk++) {
            float4 w4[NQ];
#pragma unroll
            for (int q = 0; q < NQ; q++)
                w4[q] = *(const float4*)&Ws[(kl + kk) * BN + c0 + 4 * q];
#pragma unroll
            for (int m = 0; m < TM; m++) {
                float a = (kk == 0) ? b[m].x : (kk == 1) ? b[m].y : (kk == 2) ? b[m].z : b[m].w;
#pragma unroll
                for (int q = 0; q < NQ; q++) {
                    acc[m][q].x += a * w4[q].x;
                    acc[m][q].y += a * w4[q].y;
                    acc[m][q].z += a * w4[q].z;
                    acc[m][q].w += a * w4[q].w;
                }
            }
        }
    };

    stage(0);
    loadA(0, bufA);
    __syncthreads();

#pragma unroll
    for (int c = 0; c < K / BK; c++) {
        const int k0 = c * BK;
        if (c > 0) { __syncthreads(); stage(k0); __syncthreads(); }
#pragma unroll 2
        for (int k8 = 0; k8 < BK; k8 += 8) {
            loadA(k0 + k8 + 4, bufB);              // always in range (<= K-4)
            compute(k8, bufA);
            if (k0 + k8 + 8 < K) loadA(k0 + k8 + 8, bufA);  // may cross chunk (A indep)
            compute(k8 + 4, bufB);
        }
    }

    float4 b4[NQ];
#pragma unroll
    for (int q = 0; q < NQ; q++)
        b4[q] = bias ? *(const float4*)&bias[c0 + 4 * q] : make_float4(0.f, 0.f, 0.f, 0.f);

#pragma unroll
    for (int m = 0; m < TM; m++) {
        int r = row0 + rg + 16 * m;
        if (r < M) {
#pragma unroll
            for (int q = 0; q < NQ; q++) {
                float4 o = make_float4(acc[m][q].x + b4[q].x, acc[m][q].y + b4[q].y,
                                       acc[m][q].z + b4[q].z, acc[m][q].w + b4[q].w);
                *reinterpret_cast<float4*>(&C[(long)r * BN + c0 + 4 * q]) = o;
            }
        }
    }
}

// ---------------- fused gather + selfloop + bias + LN + relu + residual ----------------
// one wave (64 lanes) per node, 2 floats per lane.

__global__ __launch_bounds__(256) void gather_post_kernel(const int* __restrict__ offsets,
                                                          const int* __restrict__ deg,
                                                          const int2* __restrict__ es,
                                                          const float* __restrict__ dinv,
                                                          const float* __restrict__ xw,
                                                          const float* __restrict__ b,
                                                          const float* __restrict__ g,
                                                          const float* __restrict__ beta,
                                                          float* __restrict__ h) {
    int wave = threadIdx.x >> 6;
    int lane = threadIdx.x & 63;
    int row = blockIdx.x * 4 + wave;
    if (row >= N_NODES) return;

    const int2* ep = es + offsets[row];
    int dg = deg[row];

    float acc0 = 0.f, acc1 = 0.f;
    int j = 0;
    for (; j + 4 <= dg; j += 4) {
        int2 e0 = ep[j + 0];
        int2 e1 = ep[j + 1];
        int2 e2 = ep[j + 2];
        int2 e3 = ep[j + 3];
        float2 v0 = *reinterpret_cast<const float2*>(&xw[(long)e0.x * HID + lane * 2]);
        float2 v1 = *reinterpret_cast<const float2*>(&xw[(long)e1.x * HID + lane * 2]);
        float2 v2 = *reinterpret_cast<const float2*>(&xw[(long)e2.x * HID + lane * 2]);
        float2 v3 = *reinterpret_cast<const float2*>(&xw[(long)e3.x * HID + lane * 2]);
        float w0 = __int_as_float(e0.y), w1 = __int_as_float(e1.y);
        float w2 = __int_as_float(e2.y), w3 = __int_as_float(e3.y);
        acc0 += v0.x * w0; acc1 += v0.y * w0;
        acc0 += v1.x * w1; acc1 += v1.y * w1;
        acc0 += v2.x * w2; acc1 += v2.y * w2;
        acc0 += v3.x * w3; acc1 += v3.y * w3;
    }
    for (; j < dg; j++) {
        int2 e0 = ep[j];
        float w0 = __int_as_float(e0.y);
        float2 v0 = *reinterpret_cast<const float2*>(&xw[(long)e0.x * HID + lane * 2]);
        acc0 += v0.x * w0; acc1 += v0.y * w0;
    }

    // self loop + bias
    float di = dinv[row];
    float sw = di * di;
    float2 xv = *reinterpret_cast<const float2*>(&xw[(long)row * HID + lane * 2]);
    float2 bv = *reinterpret_cast<const float2*>(&b[lane * 2]);
    float y0 = acc0 + xv.x * sw + bv.x;
    float y1 = acc1 + xv.y * sw + bv.y;

    // LayerNorm over 128 features (64 lanes x 2)
    float sum = y0 + y1;
#pragma unroll
    for (int o = 32; o; o >>= 1) sum += __shfl_xor(sum, o);
    float mu = sum * (1.0f / HID);

    float d0 = y0 - mu, d1 = y1 - mu;
    float vs = d0 * d0 + d1 * d1;
#pragma unroll
    for (int o = 32; o; o >>= 1) vs += __shfl_xor(vs, o);
    float rstd = rsqrtf(vs * (1.0f / HID) + LN_EPS);

    float2 gv = *reinterpret_cast<const float2*>(&g[lane * 2]);
    float2 bev = *reinterpret_cast<const float2*>(&beta[lane * 2]);
    float r0 = fmaxf(d0 * rstd * gv.x + bev.x, 0.0f);
    float r1 = fmaxf(d1 * rstd * gv.y + bev.y, 0.0f);

    float2* hp = reinterpret_cast<float2*>(&h[(long)row * HID + lane * 2]);
    float2 hv = *hp;
    hv.x += r0;
    hv.y += r1;
    *hp = hv;
}

// ---------------- launch ----------------

extern "C" void kernel_launch(void* const* d_in, const int* in_sizes, int n_in,
                              void* d_out, int out_size, void* d_ws, size_t ws_size,
                              hipStream_t stream) {
    const float* x      = (const float*)d_in[0];
    const int*   eidx   = (const int*)d_in[1];
    const float* in_W   = (const float*)d_in[2];
    const float* in_b   = (const float*)d_in[3];
    const float* conv_W = (const float*)d_in[4];
    const float* conv_b = (const float*)d_in[5];
    const float* ln_g   = (const float*)d_in[6];
    const float* ln_b   = (const float*)d_in[7];
    const float* out_W  = (const float*)d_in[8];
    const float* out_b  = (const float*)d_in[9];

    const int* src = eidx;
    const int* dst = eidx + E_EDGES;

    char* ws = (char*)d_ws;
    size_t off = 0;
    auto alloc = [&](size_t bytes) {
        void* p = ws + off;
        off += (bytes + 1023) & ~(size_t)1023;
        return p;
    };
    int*   deg       = (int*)  alloc((size_t)N_NODES * 4);
    float* dinv      = (float*)alloc((size_t)N_NODES * 4);
    int*   offsets   = (int*)  alloc((size_t)N_NODES * 4);
    int*   cursor    = (int*)  alloc((size_t)N_NODES * 4);
    int*   blockSums = (int*)  alloc((size_t)NB_SCAN * 4);
    int2*  es        = (int2*) alloc((size_t)E_EDGES * 8);
    float* h         = (float*)alloc((size_t)N_NODES * HID * 4);
    float* xw        = (float*)alloc((size_t)N_NODES * HID * 4);

    hipMemsetAsync(deg, 0, (size_t)N_NODES * 4, stream);
    deg_kernel<<<(E_EDGES + 255) / 256, 256, 0, stream>>>(dst, deg);
    dinv_kernel<<<(N_NODES + 255) / 256, 256, 0, stream>>>(deg, dinv);

    // CSR build
    block_sum_kernel<<<NB_SCAN, 256, 0, stream>>>(deg, blockSums);
    scan_blocks_kernel<<<1, 512, 0, stream>>>(blockSums, NB_SCAN);
    scan_final_kernel<<<NB_SCAN, 256, 0, stream>>>(deg, blockSums, offsets, cursor);
    bin_kernel<<<(E_EDGES + 255) / 256, 256, 0, stream>>>(src, dst, dinv, cursor, es);

    const int gemm_grid = (N_NODES + 127) / 128;   // 782

    gemm_kernel<IN_DIM, HID><<<gemm_grid, 256, 0, stream>>>(x, in_W, in_b, h, N_NODES);

    for (int l = 0; l < LAYERS; l++) {
        gemm_kernel<HID, HID><<<gemm_grid, 256, 0, stream>>>(
            h, conv_W + (size_t)l * HID * HID, nullptr, xw, N_NODES);
        gather_post_kernel<<<(N_NODES + 3) / 4, 256, 0, stream>>>(
            offsets, deg, es, dinv, xw,
            conv_b + l * HID, ln_g + l * HID, ln_b + l * HID, h);
    }

    gemm_kernel<HID, OUT_DIM><<<gemm_grid, 256, 0, stream>>>(
        h, out_W, out_b, (float*)d_out, N_NODES);
}

// Round 5
// 855.818 us; speedup vs baseline: 10.8247x; 1.7438x over previous
//
#include <hip/hip_runtime.h>
#include <hip/hip_bf16.h>

#define N_NODES 100000
#define E_EDGES 1600000
#define IN_DIM  256
#define HID     128
#define OUT_DIM 64
#define LAYERS  3
#define LN_EPS  1e-5f

typedef __attribute__((ext_vector_type(8)))  short bf16x8;   // 8 bf16 = 4 VGPRs
typedef __attribute__((ext_vector_type(16))) float f32x16;   // MFMA 32x32 accumulator

__device__ inline short f2bf(float f) {              // round-to-nearest-even
    unsigned u = __float_as_uint(f);
    unsigned r = (u + 0x7fffu + ((u >> 16) & 1u)) >> 16;
    return (short)r;
}

// ---------------- degree / dinv ----------------

__global__ __launch_bounds__(256) void deg_kernel(const int* __restrict__ dst, int* __restrict__ deg) {
    int e = blockIdx.x * 256 + threadIdx.x;
    if (e < E_EDGES) atomicAdd(&deg[dst[e]], 1);
}

__global__ __launch_bounds__(256) void dinv_kernel(const int* __restrict__ deg, float* __restrict__ dinv) {
    int i = blockIdx.x * 256 + threadIdx.x;
    if (i < N_NODES) dinv[i] = rsqrtf((float)(deg[i] + 1));  // +1 = self loop
}

// ---------------- CSR build ----------------

#define NB_SCAN ((N_NODES + 255) / 256)   // 391

__global__ __launch_bounds__(256) void block_sum_kernel(const int* __restrict__ deg,
                                                        int* __restrict__ blockSums) {
    __shared__ int s[256];
    int i = blockIdx.x * 256 + threadIdx.x;
    s[threadIdx.x] = (i < N_NODES) ? deg[i] : 0;
    __syncthreads();
#pragma unroll
    for (int o = 128; o; o >>= 1) {
        if (threadIdx.x < o) s[threadIdx.x] += s[threadIdx.x + o];
        __syncthreads();
    }
    if (threadIdx.x == 0) blockSums[blockIdx.x] = s[0];
}

__global__ __launch_bounds__(512) void scan_blocks_kernel(int* __restrict__ blockSums, int nb) {
    __shared__ int s[512];
    int t = threadIdx.x;
    int orig = (t < nb) ? blockSums[t] : 0;
    s[t] = orig;
    __syncthreads();
#pragma unroll
    for (int o = 1; o < 512; o <<= 1) {
        int v = (t >= o) ? s[t - o] : 0;
        __syncthreads();
        s[t] += v;
        __syncthreads();
    }
    if (t < nb) blockSums[t] = s[t] - orig;   // exclusive
}

__global__ __launch_bounds__(256) void scan_final_kernel(const int* __restrict__ deg,
                                                         const int* __restrict__ blockSums,
                                                         int* __restrict__ offsets,
                                                         int* __restrict__ cursor) {
    __shared__ int s[256];
    int i = blockIdx.x * 256 + threadIdx.x;
    int t = threadIdx.x;
    int v = (i < N_NODES) ? deg[i] : 0;
    s[t] = v;
    __syncthreads();
#pragma unroll
    for (int o = 1; o < 256; o <<= 1) {
        int u = (t >= o) ? s[t - o] : 0;
        __syncthreads();
        s[t] += u;
        __syncthreads();
    }
    if (i < N_NODES) {
        int excl = s[t] - v + blockSums[blockIdx.x];
        offsets[i] = excl;
        cursor[i] = excl;
    }
}

__global__ __launch_bounds__(256) void bin_kernel(const int* __restrict__ src,
                                                  const int* __restrict__ dst,
                                                  const float* __restrict__ dinv,
                                                  int* __restrict__ cursor,
                                                  int2* __restrict__ es) {
    int e = blockIdx.x * 256 + threadIdx.x;
    if (e >= E_EDGES) return;
    int s = src[e], d = dst[e];
    int p = atomicAdd(&cursor[d], 1);
    es[p] = make_int2(s, __float_as_int(dinv[s] * dinv[d]));
}

// ---------------- weight transpose+cast: WT[n][k] (bf16) from W[k][n] (f32) ----------------

template<int K, int N>
__global__ __launch_bounds__(256) void wt_kernel(const float* __restrict__ W, short* __restrict__ WT) {
    int idx = blockIdx.x * 256 + threadIdx.x;
    if (idx >= K * N) return;
    int n = idx / K, k = idx % K;
    WT[idx] = f2bf(W[(long)k * N + n]);
}

// ---------------- MFMA bf16 GEMM: C[M,N] = A[M,KT] @ W[KT,N] (+bias) ----------------
// WT[N][KT] bf16 staged in LDS (BK=128 chunks, row pad +16B); A streamed from
// global per-fragment. Block = 4 waves x 64 rows = 256 rows. Per wave per
// 16-k step: 2 A-frags (16B/lane) + N/32 B-frags (ds_read_b128) + 2*N/32 MFMA.
// v_mfma_f32_32x32x16_bf16: A row=lane&31,k=(lane>>5)*8+j; C col=lane&31,
// row=(reg&3)+8*(reg>>2)+4*(lane>>5)   [m74/m101 verified mapping]

template<int KT, int N, bool ABF>
__global__ __launch_bounds__(256) void mfma_gemm(const void* __restrict__ Av,
                                                 const short* __restrict__ WT,
                                                 const float* __restrict__ bias,
                                                 float* __restrict__ C,
                                                 short* __restrict__ Cb,
                                                 int M) {
    constexpr int BK = 128;
    constexpr int SR = BK * 2 + 16;          // LDS row stride bytes (pad vs 256B power-of-2)
    constexpr int NT = N / 32;

    __shared__ char lds[N * SR];

    const int tid = threadIdx.x;
    const int wv = tid >> 6;
    const int ln = tid & 63;
    const int l31 = ln & 31;
    const int lh = ln >> 5;
    const int row_base = blockIdx.x * 256 + wv * 64;

    f32x16 acc[2][NT];
#pragma unroll
    for (int rt = 0; rt < 2; rt++)
#pragma unroll
        for (int nt = 0; nt < NT; nt++)
#pragma unroll
            for (int r = 0; r < 16; r++) acc[rt][nt][r] = 0.f;

    // clamped A row bases (element offset of this lane's k-group included)
    long aoff[2];
#pragma unroll
    for (int rt = 0; rt < 2; rt++) {
        int r = row_base + rt * 32 + l31;
        if (r > M - 1) r = M - 1;
        aoff[rt] = (long)r * KT + lh * 8;
    }

#pragma unroll
    for (int c = 0; c < KT / BK; c++) {
        __syncthreads();
        // stage WT chunk c -> LDS (reg-staged 16B copies, once per chunk)
#pragma unroll
        for (int i = tid; i < N * 16; i += 256) {
            int n = i >> 4, kb = (i & 15) << 4;
            float4 v = *(const float4*)((const char*)WT + (long)n * (KT * 2) + c * (BK * 2) + kb);
            *(float4*)(&lds[n * SR + kb]) = v;
        }
        __syncthreads();

#pragma unroll
        for (int ks = 0; ks < BK / 16; ks++) {
            bf16x8 a[2];
#pragma unroll
            for (int rt = 0; rt < 2; rt++) {
                if (ABF) {
                    a[rt] = *(const bf16x8*)((const short*)Av + aoff[rt] + c * BK + ks * 16);
                } else {
                    const float* ap = (const float*)Av + aoff[rt] + c * BK + ks * 16;
                    float4 f0 = *(const float4*)(ap);
                    float4 f1 = *(const float4*)(ap + 4);
                    bf16x8 t;
                    t[0] = f2bf(f0.x); t[1] = f2bf(f0.y); t[2] = f2bf(f0.z); t[3] = f2bf(f0.w);
                    t[4] = f2bf(f1.x); t[5] = f2bf(f1.y); t[6] = f2bf(f1.z); t[7] = f2bf(f1.w);
                    a[rt] = t;
                }
            }
            bf16x8 b[NT];
#pragma unroll
            for (int nt = 0; nt < NT; nt++) {
                int n = nt * 32 + l31;
                b[nt] = *(const bf16x8*)(&lds[n * SR + ks * 32 + lh * 16]);
            }
#pragma unroll
            for (int nt = 0; nt < NT; nt++) {
                acc[0][nt] = __builtin_amdgcn_mfma_f32_32x32x16_bf16(a[0], b[nt], acc[0][nt], 0, 0, 0);
                acc[1][nt] = __builtin_amdgcn_mfma_f32_32x32x16_bf16(a[1], b[nt], acc[1][nt], 0, 0, 0);
            }
        }
    }

    // epilogue
#pragma unroll
    for (int rt = 0; rt < 2; rt++) {
#pragma unroll
        for (int nt = 0; nt < NT; nt++) {
            int col = nt * 32 + l31;
            float bv = bias ? bias[col] : 0.f;
#pragma unroll
            for (int r = 0; r < 16; r++) {
                int row = row_base + rt * 32 + (r & 3) + 8 * (r >> 2) + 4 * lh;
                if (row < M) {
                    float v = acc[rt][nt][r] + bv;
                    C[(long)row * N + col] = v;
                    if (Cb) Cb[(long)row * N + col] = f2bf(v);
                }
            }
        }
    }
}

// ---------------- fused gather + selfloop + bias + LN + relu + residual ----------------
// one wave per node, 2 floats per lane; writes f32 h and bf16 hb.

__global__ __launch_bounds__(256) void gather_post_kernel(const int* __restrict__ offsets,
                                                          const int* __restrict__ deg,
                                                          const int2* __restrict__ es,
                                                          const float* __restrict__ dinv,
                                                          const float* __restrict__ xw,
                                                          const float* __restrict__ b,
                                                          const float* __restrict__ g,
                                                          const float* __restrict__ beta,
                                                          float* __restrict__ h,
                                                          short* __restrict__ hb) {
    int wave = threadIdx.x >> 6;
    int lane = threadIdx.x & 63;
    int row = blockIdx.x * 4 + wave;
    if (row >= N_NODES) return;

    const int2* ep = es + offsets[row];
    int dg = deg[row];

    float acc0 = 0.f, acc1 = 0.f;
    int j = 0;
    for (; j + 4 <= dg; j += 4) {
        int2 e0 = ep[j + 0];
        int2 e1 = ep[j + 1];
        int2 e2 = ep[j + 2];
        int2 e3 = ep[j + 3];
        float2 v0 = *reinterpret_cast<const float2*>(&xw[(long)e0.x * HID + lane * 2]);
        float2 v1 = *reinterpret_cast<const float2*>(&xw[(long)e1.x * HID + lane * 2]);
        float2 v2 = *reinterpret_cast<const float2*>(&xw[(long)e2.x * HID + lane * 2]);
        float2 v3 = *reinterpret_cast<const float2*>(&xw[(long)e3.x * HID + lane * 2]);
        float w0 = __int_as_float(e0.y), w1 = __int_as_float(e1.y);
        float w2 = __int_as_float(e2.y), w3 = __int_as_float(e3.y);
        acc0 += v0.x * w0; acc1 += v0.y * w0;
        acc0 += v1.x * w1; acc1 += v1.y * w1;
        acc0 += v2.x * w2; acc1 += v2.y * w2;
        acc0 += v3.x * w3; acc1 += v3.y * w3;
    }
    for (; j < dg; j++) {
        int2 e0 = ep[j];
        float w0 = __int_as_float(e0.y);
        float2 v0 = *reinterpret_cast<const float2*>(&xw[(long)e0.x * HID + lane * 2]);
        acc0 += v0.x * w0; acc1 += v0.y * w0;
    }

    float di = dinv[row];
    float sw = di * di;
    float2 xv = *reinterpret_cast<const float2*>(&xw[(long)row * HID + lane * 2]);
    float2 bv = *reinterpret_cast<const float2*>(&b[lane * 2]);
    float y0 = acc0 + xv.x * sw + bv.x;
    float y1 = acc1 + xv.y * sw + bv.y;

    float sum = y0 + y1;
#pragma unroll
    for (int o = 32; o; o >>= 1) sum += __shfl_xor(sum, o);
    float mu = sum * (1.0f / HID);

    float d0 = y0 - mu, d1 = y1 - mu;
    float vs = d0 * d0 + d1 * d1;
#pragma unroll
    for (int o = 32; o; o >>= 1) vs += __shfl_xor(vs, o);
    float rstd = rsqrtf(vs * (1.0f / HID) + LN_EPS);

    float2 gv = *reinterpret_cast<const float2*>(&g[lane * 2]);
    float2 bev = *reinterpret_cast<const float2*>(&beta[lane * 2]);
    float r0 = fmaxf(d0 * rstd * gv.x + bev.x, 0.0f);
    float r1 = fmaxf(d1 * rstd * gv.y + bev.y, 0.0f);

    float2* hp = reinterpret_cast<float2*>(&h[(long)row * HID + lane * 2]);
    float2 hv = *hp;
    hv.x += r0;
    hv.y += r1;
    *hp = hv;

    unsigned pk = ((unsigned)(unsigned short)f2bf(hv.y) << 16) |
                  (unsigned)(unsigned short)f2bf(hv.x);
    *reinterpret_cast<unsigned*>(&hb[(long)row * HID + lane * 2]) = pk;
}

// ---------------- launch ----------------

extern "C" void kernel_launch(void* const* d_in, const int* in_sizes, int n_in,
                              void* d_out, int out_size, void* d_ws, size_t ws_size,
                              hipStream_t stream) {
    const float* x      = (const float*)d_in[0];
    const int*   eidx   = (const int*)d_in[1];
    const float* in_W   = (const float*)d_in[2];
    const float* in_b   = (const float*)d_in[3];
    const float* conv_W = (const float*)d_in[4];
    const float* conv_b = (const float*)d_in[5];
    const float* ln_g   = (const float*)d_in[6];
    const float* ln_b   = (const float*)d_in[7];
    const float* out_W  = (const float*)d_in[8];
    const float* out_b  = (const float*)d_in[9];

    const int* src = eidx;
    const int* dst = eidx + E_EDGES;

    char* ws = (char*)d_ws;
    size_t off = 0;
    auto alloc = [&](size_t bytes) {
        void* p = ws + off;
        off += (bytes + 1023) & ~(size_t)1023;
        return p;
    };
    int*   deg       = (int*)  alloc((size_t)N_NODES * 4);
    float* dinv      = (float*)alloc((size_t)N_NODES * 4);
    int*   offsets   = (int*)  alloc((size_t)N_NODES * 4);
    int*   cursor    = (int*)  alloc((size_t)N_NODES * 4);
    int*   blockSums = (int*)  alloc((size_t)NB_SCAN * 4);
    int2*  es        = (int2*) alloc((size_t)E_EDGES * 8);
    float* h         = (float*)alloc((size_t)N_NODES * HID * 4);
    float* xw        = (float*)alloc((size_t)N_NODES * HID * 4);
    short* hb        = (short*)alloc((size_t)N_NODES * HID * 2);
    short* in_WT     = (short*)alloc((size_t)IN_DIM * HID * 2);
    short* conv_WT   = (short*)alloc((size_t)LAYERS * HID * HID * 2);
    short* out_WT    = (short*)alloc((size_t)HID * OUT_DIM * 2);

    hipMemsetAsync(deg, 0, (size_t)N_NODES * 4, stream);
    deg_kernel<<<(E_EDGES + 255) / 256, 256, 0, stream>>>(dst, deg);
    dinv_kernel<<<(N_NODES + 255) / 256, 256, 0, stream>>>(deg, dinv);

    // CSR build
    block_sum_kernel<<<NB_SCAN, 256, 0, stream>>>(deg, blockSums);
    scan_blocks_kernel<<<1, 512, 0, stream>>>(blockSums, NB_SCAN);
    scan_final_kernel<<<NB_SCAN, 256, 0, stream>>>(deg, blockSums, offsets, cursor);
    bin_kernel<<<(E_EDGES + 255) / 256, 256, 0, stream>>>(src, dst, dinv, cursor, es);

    // weight cast+transpose
    wt_kernel<IN_DIM, HID><<<(IN_DIM * HID + 255) / 256, 256, 0, stream>>>(in_W, in_WT);
    for (int l = 0; l < LAYERS; l++)
        wt_kernel<HID, HID><<<(HID * HID + 255) / 256, 256, 0, stream>>>(
            conv_W + (size_t)l * HID * HID, conv_WT + (size_t)l * HID * HID);
    wt_kernel<HID, OUT_DIM><<<(HID * OUT_DIM + 255) / 256, 256, 0, stream>>>(out_W, out_WT);

    const int ggrid = (N_NODES + 255) / 256;   // 391

    // h = x @ in_W + in_b   (A = f32 x, converted in-flight)
    mfma_gemm<IN_DIM, HID, false><<<ggrid, 256, 0, stream>>>(
        (const void*)x, in_WT, in_b, h, hb, N_NODES);

    for (int l = 0; l < LAYERS; l++) {
        mfma_gemm<HID, HID, true><<<ggrid, 256, 0, stream>>>(
            (const void*)hb, conv_WT + (size_t)l * HID * HID, nullptr, xw, nullptr, N_NODES);
        gather_post_kernel<<<(N_NODES + 3) / 4, 256, 0, stream>>>(
            offsets, deg, es, dinv, xw,
            conv_b + l * HID, ln_g + l * HID, ln_b + l * HID, h, hb);
    }

    mfma_gemm<HID, OUT_DIM, true><<<ggrid, 256, 0, stream>>>(
        (const void*)hb, out_WT, out_b, (float*)d_out, nullptr, N_NODES);
}

// Round 8
// 800.214 us; speedup vs baseline: 11.5769x; 1.0695x over previous
//
#include <hip/hip_runtime.h>
#include <hip/hip_bf16.h>

#define N_NODES 100000
#define E_EDGES 1600000
#define IN_DIM  256
#define HID     128
#define OUT_DIM 64
#define LAYERS  3
#define LN_EPS  1e-5f

typedef __attribute__((ext_vector_type(8)))  short bf16x8;   // 8 bf16 = 4 VGPRs
typedef __attribute__((ext_vector_type(16))) float f32x16;   // MFMA 32x32 accumulator

__device__ inline short f2bf(float f) {              // round-to-nearest-even
    unsigned u = __float_as_uint(f);
    unsigned r = (u + 0x7fffu + ((u >> 16) & 1u)) >> 16;
    return (short)r;
}
__device__ inline float bflo(unsigned u) { return __uint_as_float(u << 16); }
__device__ inline float bfhi(unsigned u) { return __uint_as_float(u & 0xffff0000u); }

// ---------------- degree / dinv ----------------

__global__ __launch_bounds__(256) void deg_kernel(const int* __restrict__ dst, int* __restrict__ deg) {
    int e = blockIdx.x * 256 + threadIdx.x;
    if (e < E_EDGES) atomicAdd(&deg[dst[e]], 1);
}

__global__ __launch_bounds__(256) void dinv_kernel(const int* __restrict__ deg, float* __restrict__ dinv) {
    int i = blockIdx.x * 256 + threadIdx.x;
    if (i < N_NODES) dinv[i] = rsqrtf((float)(deg[i] + 1));  // +1 = self loop
}

// ---------------- CSR build ----------------

#define NB_SCAN ((N_NODES + 255) / 256)   // 391

__global__ __launch_bounds__(256) void block_sum_kernel(const int* __restrict__ deg,
                                                        int* __restrict__ blockSums) {
    __shared__ int s[256];
    int i = blockIdx.x * 256 + threadIdx.x;
    s[threadIdx.x] = (i < N_NODES) ? deg[i] : 0;
    __syncthreads();
#pragma unroll
    for (int o = 128; o; o >>= 1) {
        if (threadIdx.x < o) s[threadIdx.x] += s[threadIdx.x + o];
        __syncthreads();
    }
    if (threadIdx.x == 0) blockSums[blockIdx.x] = s[0];
}

__global__ __launch_bounds__(512) void scan_blocks_kernel(int* __restrict__ blockSums, int nb) {
    __shared__ int s[512];
    int t = threadIdx.x;
    int orig = (t < nb) ? blockSums[t] : 0;
    s[t] = orig;
    __syncthreads();
#pragma unroll
    for (int o = 1; o < 512; o <<= 1) {
        int v = (t >= o) ? s[t - o] : 0;
        __syncthreads();
        s[t] += v;
        __syncthreads();
    }
    if (t < nb) blockSums[t] = s[t] - orig;   // exclusive
}

__global__ __launch_bounds__(256) void scan_final_kernel(const int* __restrict__ deg,
                                                         const int* __restrict__ blockSums,
                                                         int* __restrict__ offsets,
                                                         int* __restrict__ cursor) {
    __shared__ int s[256];
    int i = blockIdx.x * 256 + threadIdx.x;
    int t = threadIdx.x;
    int v = (i < N_NODES) ? deg[i] : 0;
    s[t] = v;
    __syncthreads();
#pragma unroll
    for (int o = 1; o < 256; o <<= 1) {
        int u = (t >= o) ? s[t - o] : 0;
        __syncthreads();
        s[t] += u;
        __syncthreads();
    }
    if (i < N_NODES) {
        int excl = s[t] - v + blockSums[blockIdx.x];
        offsets[i] = excl;
        cursor[i] = excl;
    }
}

__global__ __launch_bounds__(256) void bin_kernel(const int* __restrict__ src,
                                                  const int* __restrict__ dst,
                                                  const float* __restrict__ dinv,
                                                  int* __restrict__ cursor,
                                                  int2* __restrict__ es) {
    int e = blockIdx.x * 256 + threadIdx.x;
    if (e >= E_EDGES) return;
    int s = src[e], d = dst[e];
    int p = atomicAdd(&cursor[d], 1);
    es[p] = make_int2(s, __float_as_int(dinv[s] * dinv[d]));
}

// ---------------- weight transpose+cast: WT[n][k] (bf16) from W[k][n] (f32) ----------------

template<int K, int N>
__global__ __launch_bounds__(256) void wt_kernel(const float* __restrict__ W, short* __restrict__ WT) {
    int idx = blockIdx.x * 256 + threadIdx.x;
    if (idx >= K * N) return;
    int n = idx / K, k = idx % K;
    WT[idx] = f2bf(W[(long)k * N + n]);
}

// ---------------- MFMA bf16 GEMM: C[M,N] = A[M,KT] @ W[KT,N] (+bias) ----------------
// WT[N][KT] bf16 staged in LDS (BK=128 chunks, row pad +16B); A streamed from
// global per-fragment. Block = 4 waves x 64 rows = 256 rows.
// v_mfma_f32_32x32x16_bf16 C layout: col=lane&31, row=(reg&3)+8*(reg>>2)+4*(lane>>5)

template<int KT, int N, bool ABF>
__global__ __launch_bounds__(256) void mfma_gemm(const void* __restrict__ Av,
                                                 const short* __restrict__ WT,
                                                 const float* __restrict__ bias,
                                                 float* __restrict__ C,
                                                 short* __restrict__ Cb,
                                                 int M) {
    constexpr int BK = 128;
    constexpr int SR = BK * 2 + 16;          // LDS row stride bytes
    constexpr int NT = N / 32;

    __shared__ char lds[N * SR];

    const int tid = threadIdx.x;
    const int wv = tid >> 6;
    const int ln = tid & 63;
    const int l31 = ln & 31;
    const int lh = ln >> 5;
    const int row_base = blockIdx.x * 256 + wv * 64;

    f32x16 acc[2][NT];
#pragma unroll
    for (int rt = 0; rt < 2; rt++)
#pragma unroll
        for (int nt = 0; nt < NT; nt++)
#pragma unroll
            for (int r = 0; r < 16; r++) acc[rt][nt][r] = 0.f;

    long aoff[2];
#pragma unroll
    for (int rt = 0; rt < 2; rt++) {
        int r = row_base + rt * 32 + l31;
        if (r > M - 1) r = M - 1;
        aoff[rt] = (long)r * KT + lh * 8;
    }

#pragma unroll
    for (int c = 0; c < KT / BK; c++) {
        __syncthreads();
#pragma unroll
        for (int i = tid; i < N * 16; i += 256) {
            int n = i >> 4, kb = (i & 15) << 4;
            float4 v = *(const float4*)((const char*)WT + (long)n * (KT * 2) + c * (BK * 2) + kb);
            *(float4*)(&lds[n * SR + kb]) = v;
        }
        __syncthreads();

#pragma unroll
        for (int ks = 0; ks < BK / 16; ks++) {
            bf16x8 a[2];
#pragma unroll
            for (int rt = 0; rt < 2; rt++) {
                if (ABF) {
                    a[rt] = *(const bf16x8*)((const short*)Av + aoff[rt] + c * BK + ks * 16);
                } else {
                    const float* ap = (const float*)Av + aoff[rt] + c * BK + ks * 16;
                    float4 f0 = *(const float4*)(ap);
                    float4 f1 = *(const float4*)(ap + 4);
                    bf16x8 t;
                    t[0] = f2bf(f0.x); t[1] = f2bf(f0.y); t[2] = f2bf(f0.z); t[3] = f2bf(f0.w);
                    t[4] = f2bf(f1.x); t[5] = f2bf(f1.y); t[6] = f2bf(f1.z); t[7] = f2bf(f1.w);
                    a[rt] = t;
                }
            }
            bf16x8 b[NT];
#pragma unroll
            for (int nt = 0; nt < NT; nt++) {
                int n = nt * 32 + l31;
                b[nt] = *(const bf16x8*)(&lds[n * SR + ks * 32 + lh * 16]);
            }
#pragma unroll
            for (int nt = 0; nt < NT; nt++) {
                acc[0][nt] = __builtin_amdgcn_mfma_f32_32x32x16_bf16(a[0], b[nt], acc[0][nt], 0, 0, 0);
                acc[1][nt] = __builtin_amdgcn_mfma_f32_32x32x16_bf16(a[1], b[nt], acc[1][nt], 0, 0, 0);
            }
        }
    }

    // epilogue
#pragma unroll
    for (int rt = 0; rt < 2; rt++) {
#pragma unroll
        for (int nt = 0; nt < NT; nt++) {
            int col = nt * 32 + l31;
            float bv = bias ? bias[col] : 0.f;
#pragma unroll
            for (int r = 0; r < 16; r++) {
                int row = row_base + rt * 32 + (r & 3) + 8 * (r >> 2) + 4 * lh;
                if (row < M) {
                    float v = acc[rt][nt][r] + bv;
                    if (C)  C[(long)row * N + col] = v;
                    if (Cb) Cb[(long)row * N + col] = f2bf(v);
                }
            }
        }
    }
}

// ---------------- fused gather + selfloop + bias + LN + relu + residual ----------------
// one wave per node, 2 features per lane; gathers bf16 xwb rows, f32 accum.

__global__ __launch_bounds__(256) void gather_post_kernel(const int* __restrict__ offsets,
                                                          const int* __restrict__ deg,
                                                          const int2* __restrict__ es,
                                                          const float* __restrict__ dinv,
                                                          const short* __restrict__ xwb,
                                                          const float* __restrict__ b,
                                                          const float* __restrict__ g,
                                                          const float* __restrict__ beta,
                                                          float* __restrict__ h,
                                                          short* __restrict__ hb) {
    int wave = threadIdx.x >> 6;
    int lane = threadIdx.x & 63;
    int row = blockIdx.x * 4 + wave;
    if (row >= N_NODES) return;

    const int2* ep = es + offsets[row];
    int dg = deg[row];

    float acc0 = 0.f, acc1 = 0.f;
    int j = 0;
    for (; j + 4 <= dg; j += 4) {
        int2 e0 = ep[j + 0];
        int2 e1 = ep[j + 1];
        int2 e2 = ep[j + 2];
        int2 e3 = ep[j + 3];
        unsigned u0 = *(const unsigned*)(&xwb[(long)e0.x * HID + lane * 2]);
        unsigned u1 = *(const unsigned*)(&xwb[(long)e1.x * HID + lane * 2]);
        unsigned u2 = *(const unsigned*)(&xwb[(long)e2.x * HID + lane * 2]);
        unsigned u3 = *(const unsigned*)(&xwb[(long)e3.x * HID + lane * 2]);
        float w0 = __int_as_float(e0.y), w1 = __int_as_float(e1.y);
        float w2 = __int_as_float(e2.y), w3 = __int_as_float(e3.y);
        acc0 += bflo(u0) * w0; acc1 += bfhi(u0) * w0;
        acc0 += bflo(u1) * w1; acc1 += bfhi(u1) * w1;
        acc0 += bflo(u2) * w2; acc1 += bfhi(u2) * w2;
        acc0 += bflo(u3) * w3; acc1 += bfhi(u3) * w3;
    }
    for (; j < dg; j++) {
        int2 e0 = ep[j];
        float w0 = __int_as_float(e0.y);
        unsigned u0 = *(const unsigned*)(&xwb[(long)e0.x * HID + lane * 2]);
        acc0 += bflo(u0) * w0; acc1 += bfhi(u0) * w0;
    }

    float di = dinv[row];
    float sw = di * di;
    unsigned ux = *(const unsigned*)(&xwb[(long)row * HID + lane * 2]);
    float2 bv = *reinterpret_cast<const float2*>(&b[lane * 2]);
    float y0 = acc0 + bflo(ux) * sw + bv.x;
    float y1 = acc1 + bfhi(ux) * sw + bv.y;

    float sum = y0 + y1;
#pragma unroll
    for (int o = 32; o; o >>= 1) sum += __shfl_xor(sum, o);
    float mu = sum * (1.0f / HID);

    float d0 = y0 - mu, d1 = y1 - mu;
    float vs = d0 * d0 + d1 * d1;
#pragma unroll
    for (int o = 32; o; o >>= 1) vs += __shfl_xor(vs, o);
    float rstd = rsqrtf(vs * (1.0f / HID) + LN_EPS);

    float2 gv = *reinterpret_cast<const float2*>(&g[lane * 2]);
    float2 bev = *reinterpret_cast<const float2*>(&beta[lane * 2]);
    float r0 = fmaxf(d0 * rstd * gv.x + bev.x, 0.0f);
    float r1 = fmaxf(d1 * rstd * gv.y + bev.y, 0.0f);

    float2* hp = reinterpret_cast<float2*>(&h[(long)row * HID + lane * 2]);
    float2 hv = *hp;
    hv.x += r0;
    hv.y += r1;
    *hp = hv;

    unsigned pk = ((unsigned)(unsigned short)f2bf(hv.y) << 16) |
                  (unsigned)(unsigned short)f2bf(hv.x);
    *reinterpret_cast<unsigned*>(&hb[(long)row * HID + lane * 2]) = pk;
}

// ---------------- launch ----------------

extern "C" void kernel_launch(void* const* d_in, const int* in_sizes, int n_in,
                              void* d_out, int out_size, void* d_ws, size_t ws_size,
                              hipStream_t stream) {
    const float* x      = (const float*)d_in[0];
    const int*   eidx   = (const int*)d_in[1];
    const float* in_W   = (const float*)d_in[2];
    const float* in_b   = (const float*)d_in[3];
    const float* conv_W = (const float*)d_in[4];
    const float* conv_b = (const float*)d_in[5];
    const float* ln_g   = (const float*)d_in[6];
    const float* ln_b   = (const float*)d_in[7];
    const float* out_W  = (const float*)d_in[8];
    const float* out_b  = (const float*)d_in[9];

    const int* src = eidx;
    const int* dst = eidx + E_EDGES;

    char* ws = (char*)d_ws;
    size_t off = 0;
    auto alloc = [&](size_t bytes) {
        void* p = ws + off;
        off += (bytes + 1023) & ~(size_t)1023;
        return p;
    };
    int*   deg       = (int*)  alloc((size_t)N_NODES * 4);
    float* dinv      = (float*)alloc((size_t)N_NODES * 4);
    int*   offsets   = (int*)  alloc((size_t)N_NODES * 4);
    int*   cursor    = (int*)  alloc((size_t)N_NODES * 4);
    int*   blockSums = (int*)  alloc((size_t)NB_SCAN * 4);
    int2*  es        = (int2*) alloc((size_t)E_EDGES * 8);
    float* h         = (float*)alloc((size_t)N_NODES * HID * 4);
    short* hb        = (short*)alloc((size_t)N_NODES * HID * 2);
    short* xwb       = (short*)alloc((size_t)N_NODES * HID * 2);
    short* in_WT     = (short*)alloc((size_t)IN_DIM * HID * 2);
    short* conv_WT   = (short*)alloc((size_t)LAYERS * HID * HID * 2);
    short* out_WT    = (short*)alloc((size_t)HID * OUT_DIM * 2);

    hipMemsetAsync(deg, 0, (size_t)N_NODES * 4, stream);
    deg_kernel<<<(E_EDGES + 255) / 256, 256, 0, stream>>>(dst, deg);
    dinv_kernel<<<(N_NODES + 255) / 256, 256, 0, stream>>>(deg, dinv);

    // CSR build
    block_sum_kernel<<<NB_SCAN, 256, 0, stream>>>(deg, blockSums);
    scan_blocks_kernel<<<1, 512, 0, stream>>>(blockSums, NB_SCAN);
    scan_final_kernel<<<NB_SCAN, 256, 0, stream>>>(deg, blockSums, offsets, cursor);
    bin_kernel<<<(E_EDGES + 255) / 256, 256, 0, stream>>>(src, dst, dinv, cursor, es);

    // weight cast+transpose
    wt_kernel<IN_DIM, HID><<<(IN_DIM * HID + 255) / 256, 256, 0, stream>>>(in_W, in_WT);
    for (int l = 0; l < LAYERS; l++)
        wt_kernel<HID, HID><<<(HID * HID + 255) / 256, 256, 0, stream>>>(
            conv_W + (size_t)l * HID * HID, conv_WT + (size_t)l * HID * HID);
    wt_kernel<HID, OUT_DIM><<<(HID * OUT_DIM + 255) / 256, 256, 0, stream>>>(out_W, out_WT);

    const int ggrid = (N_NODES + 255) / 256;   // 391

    // h = x @ in_W + in_b   (A = f32 x, converted in-flight)
    mfma_gemm<IN_DIM, HID, false><<<ggrid, 256, 0, stream>>>(
        (const void*)x, in_WT, in_b, h, hb, N_NODES);

    for (int l = 0; l < LAYERS; l++) {
        // xwb = hb @ conv_W   (bf16 output only)
        mfma_gemm<HID, HID, true><<<ggrid, 256, 0, stream>>>(
            (const void*)hb, conv_WT + (size_t)l * HID * HID, nullptr, nullptr, xwb, N_NODES);
        gather_post_kernel<<<(N_NODES + 3) / 4, 256, 0, stream>>>(
            offsets, deg, es, dinv, xwb,
            conv_b + l * HID, ln_g + l * HID, ln_b + l * HID, h, hb);
    }

    mfma_gemm<HID, OUT_DIM, true><<<ggrid, 256, 0, stream>>>(
        (const void*)hb, out_WT, out_b, (float*)d_out, nullptr, N_NODES);
}

// Round 9
// 783.529 us; speedup vs baseline: 11.8234x; 1.0213x over previous
//
#include <hip/hip_runtime.h>
#include <hip/hip_bf16.h>

#define N_NODES 100000
#define E_EDGES 1600000
#define IN_DIM  256
#define HID     128
#define OUT_DIM 64
#define LAYERS  3
#define LN_EPS  1e-5f

typedef __attribute__((ext_vector_type(8)))  short bf16x8;   // 8 bf16 = 4 VGPRs
typedef __attribute__((ext_vector_type(16))) float f32x16;   // MFMA 32x32 accumulator

__device__ inline short f2bf(float f) {              // round-to-nearest-even
    unsigned u = __float_as_uint(f);
    unsigned r = (u + 0x7fffu + ((u >> 16) & 1u)) >> 16;
    return (short)r;
}
__device__ inline float bflo(unsigned u) { return __uint_as_float(u << 16); }
__device__ inline float bfhi(unsigned u) { return __uint_as_float(u & 0xffff0000u); }

// ---------------- degree / dinv ----------------

__global__ __launch_bounds__(256) void deg_kernel(const int* __restrict__ dst, int* __restrict__ deg) {
    int e = blockIdx.x * 256 + threadIdx.x;
    if (e < E_EDGES) atomicAdd(&deg[dst[e]], 1);
}

__global__ __launch_bounds__(256) void dinv_kernel(const int* __restrict__ deg, float* __restrict__ dinv) {
    int i = blockIdx.x * 256 + threadIdx.x;
    if (i < N_NODES) dinv[i] = rsqrtf((float)(deg[i] + 1));  // +1 = self loop
}

// ---------------- CSR build ----------------

#define NB_SCAN ((N_NODES + 255) / 256)   // 391

__global__ __launch_bounds__(256) void block_sum_kernel(const int* __restrict__ deg,
                                                        int* __restrict__ blockSums) {
    __shared__ int s[256];
    int i = blockIdx.x * 256 + threadIdx.x;
    s[threadIdx.x] = (i < N_NODES) ? deg[i] : 0;
    __syncthreads();
#pragma unroll
    for (int o = 128; o; o >>= 1) {
        if (threadIdx.x < o) s[threadIdx.x] += s[threadIdx.x + o];
        __syncthreads();
    }
    if (threadIdx.x == 0) blockSums[blockIdx.x] = s[0];
}

__global__ __launch_bounds__(512) void scan_blocks_kernel(int* __restrict__ blockSums, int nb) {
    __shared__ int s[512];
    int t = threadIdx.x;
    int orig = (t < nb) ? blockSums[t] : 0;
    s[t] = orig;
    __syncthreads();
#pragma unroll
    for (int o = 1; o < 512; o <<= 1) {
        int v = (t >= o) ? s[t - o] : 0;
        __syncthreads();
        s[t] += v;
        __syncthreads();
    }
    if (t < nb) blockSums[t] = s[t] - orig;   // exclusive
}

__global__ __launch_bounds__(256) void scan_final_kernel(const int* __restrict__ deg,
                                                         const int* __restrict__ blockSums,
                                                         int* __restrict__ offsets,
                                                         int* __restrict__ cursor) {
    __shared__ int s[256];
    int i = blockIdx.x * 256 + threadIdx.x;
    int t = threadIdx.x;
    int v = (i < N_NODES) ? deg[i] : 0;
    s[t] = v;
    __syncthreads();
#pragma unroll
    for (int o = 1; o < 256; o <<= 1) {
        int u = (t >= o) ? s[t - o] : 0;
        __syncthreads();
        s[t] += u;
        __syncthreads();
    }
    if (i < N_NODES) {
        int excl = s[t] - v + blockSums[blockIdx.x];
        offsets[i] = excl;
        cursor[i] = excl;
    }
}

__global__ __launch_bounds__(256) void bin_kernel(const int* __restrict__ src,
                                                  const int* __restrict__ dst,
                                                  const float* __restrict__ dinv,
                                                  int* __restrict__ cursor,
                                                  int2* __restrict__ es) {
    int e = blockIdx.x * 256 + threadIdx.x;
    if (e >= E_EDGES) return;
    int s = src[e], d = dst[e];
    int p = atomicAdd(&cursor[d], 1);
    es[p] = make_int2(s, __float_as_int(dinv[s] * dinv[d]));
}

// ---------------- weight transpose+cast: WT[n][k] (bf16) from W[k][n] (f32) ----------------

template<int K, int N>
__global__ __launch_bounds__(256) void wt_kernel(const float* __restrict__ W, short* __restrict__ WT) {
    int idx = blockIdx.x * 256 + threadIdx.x;
    if (idx >= K * N) return;
    int n = idx / K, k = idx % K;
    WT[idx] = f2bf(W[(long)k * N + n]);
}

// ---------------- MFMA bf16 GEMM: C[M,N] = A[M,KT] @ W[KT,N] (+bias) ----------------
// No LDS, no barriers: WT (<=64KB) is L2/L3-resident and broadcast-read per
// fragment. Each wave owns an independent 32xN tile; grid = M/128 blocks of
// 4 waves. Fully unrolled K loop -> compiler hoists loads, deep vmcnt pipe.
// v_mfma_f32_32x32x16_bf16 C layout: col=lane&31, row=(reg&3)+8*(reg>>2)+4*(lane>>5)

template<int KT, int N, bool ABF>
__global__ __launch_bounds__(256) void mfma_gemm(const void* __restrict__ Av,
                                                 const short* __restrict__ WT,
                                                 const float* __restrict__ bias,
                                                 float* __restrict__ C,
                                                 short* __restrict__ Cb,
                                                 int M) {
    constexpr int NT = N / 32;

    const int tid = threadIdx.x;
    const int wv = tid >> 6;
    const int ln = tid & 63;
    const int l31 = ln & 31;
    const int lh = ln >> 5;
    const int row0 = blockIdx.x * 128 + wv * 32;

    int ar = row0 + l31;
    if (ar > M - 1) ar = M - 1;                  // clamp; store is guarded

    // per-lane base pointers (element units), k-offset of this lane folded in
    const short* abf = (const short*)Av + (long)ar * KT + lh * 8;
    const float* af32 = (const float*)Av + (long)ar * KT + lh * 8;
    const short* bbase[NT];
#pragma unroll
    for (int nt = 0; nt < NT; nt++)
        bbase[nt] = WT + (long)(nt * 32 + l31) * KT + lh * 8;

    f32x16 acc[NT];
#pragma unroll
    for (int nt = 0; nt < NT; nt++)
#pragma unroll
        for (int r = 0; r < 16; r++) acc[nt][r] = 0.f;

#pragma unroll
    for (int ks = 0; ks < KT / 16; ks++) {
        bf16x8 a;
        if (ABF) {
            a = *(const bf16x8*)(abf + ks * 16);
        } else {
            float4 f0 = *(const float4*)(af32 + ks * 16);
            float4 f1 = *(const float4*)(af32 + ks * 16 + 4);
            bf16x8 t;
            t[0] = f2bf(f0.x); t[1] = f2bf(f0.y); t[2] = f2bf(f0.z); t[3] = f2bf(f0.w);
            t[4] = f2bf(f1.x); t[5] = f2bf(f1.y); t[6] = f2bf(f1.z); t[7] = f2bf(f1.w);
            a = t;
        }
        bf16x8 b[NT];
#pragma unroll
        for (int nt = 0; nt < NT; nt++) b[nt] = *(const bf16x8*)(bbase[nt] + ks * 16);
#pragma unroll
        for (int nt = 0; nt < NT; nt++)
            acc[nt] = __builtin_amdgcn_mfma_f32_32x32x16_bf16(a, b[nt], acc[nt], 0, 0, 0);
    }

    // epilogue
#pragma unroll
    for (int nt = 0; nt < NT; nt++) {
        int col = nt * 32 + l31;
        float bv = bias ? bias[col] : 0.f;
#pragma unroll
        for (int r = 0; r < 16; r++) {
            int row = row0 + (r & 3) + 8 * (r >> 2) + 4 * lh;
            if (row < M) {
                float v = acc[nt][r] + bv;
                if (C)  C[(long)row * N + col] = v;
                if (Cb) Cb[(long)row * N + col] = f2bf(v);
            }
        }
    }
}

// ---------------- fused gather + selfloop + bias + LN + relu + residual ----------------
// one wave per node, 2 features per lane; gathers bf16 xwb rows, f32 accum.

__global__ __launch_bounds__(256) void gather_post_kernel(const int* __restrict__ offsets,
                                                          const int* __restrict__ deg,
                                                          const int2* __restrict__ es,
                                                          const float* __restrict__ dinv,
                                                          const short* __restrict__ xwb,
                                                          const float* __restrict__ b,
                                                          const float* __restrict__ g,
                                                          const float* __restrict__ beta,
                                                          float* __restrict__ h,
                                                          short* __restrict__ hb) {
    int wave = threadIdx.x >> 6;
    int lane = threadIdx.x & 63;
    int row = blockIdx.x * 4 + wave;
    if (row >= N_NODES) return;

    const int2* ep = es + offsets[row];
    int dg = deg[row];

    float acc0 = 0.f, acc1 = 0.f;
    int j = 0;
    for (; j + 4 <= dg; j += 4) {
        int2 e0 = ep[j + 0];
        int2 e1 = ep[j + 1];
        int2 e2 = ep[j + 2];
        int2 e3 = ep[j + 3];
        unsigned u0 = *(const unsigned*)(&xwb[(long)e0.x * HID + lane * 2]);
        unsigned u1 = *(const unsigned*)(&xwb[(long)e1.x * HID + lane * 2]);
        unsigned u2 = *(const unsigned*)(&xwb[(long)e2.x * HID + lane * 2]);
        unsigned u3 = *(const unsigned*)(&xwb[(long)e3.x * HID + lane * 2]);
        float w0 = __int_as_float(e0.y), w1 = __int_as_float(e1.y);
        float w2 = __int_as_float(e2.y), w3 = __int_as_float(e3.y);
        acc0 += bflo(u0) * w0; acc1 += bfhi(u0) * w0;
        acc0 += bflo(u1) * w1; acc1 += bfhi(u1) * w1;
        acc0 += bflo(u2) * w2; acc1 += bfhi(u2) * w2;
        acc0 += bflo(u3) * w3; acc1 += bfhi(u3) * w3;
    }
    for (; j < dg; j++) {
        int2 e0 = ep[j];
        float w0 = __int_as_float(e0.y);
        unsigned u0 = *(const unsigned*)(&xwb[(long)e0.x * HID + lane * 2]);
        acc0 += bflo(u0) * w0; acc1 += bfhi(u0) * w0;
    }

    float di = dinv[row];
    float sw = di * di;
    unsigned ux = *(const unsigned*)(&xwb[(long)row * HID + lane * 2]);
    float2 bv = *reinterpret_cast<const float2*>(&b[lane * 2]);
    float y0 = acc0 + bflo(ux) * sw + bv.x;
    float y1 = acc1 + bfhi(ux) * sw + bv.y;

    float sum = y0 + y1;
#pragma unroll
    for (int o = 32; o; o >>= 1) sum += __shfl_xor(sum, o);
    float mu = sum * (1.0f / HID);

    float d0 = y0 - mu, d1 = y1 - mu;
    float vs = d0 * d0 + d1 * d1;
#pragma unroll
    for (int o = 32; o; o >>= 1) vs += __shfl_xor(vs, o);
    float rstd = rsqrtf(vs * (1.0f / HID) + LN_EPS);

    float2 gv = *reinterpret_cast<const float2*>(&g[lane * 2]);
    float2 bev = *reinterpret_cast<const float2*>(&beta[lane * 2]);
    float r0 = fmaxf(d0 * rstd * gv.x + bev.x, 0.0f);
    float r1 = fmaxf(d1 * rstd * gv.y + bev.y, 0.0f);

    float2* hp = reinterpret_cast<float2*>(&h[(long)row * HID + lane * 2]);
    float2 hv = *hp;
    hv.x += r0;
    hv.y += r1;
    *hp = hv;

    unsigned pk = ((unsigned)(unsigned short)f2bf(hv.y) << 16) |
                  (unsigned)(unsigned short)f2bf(hv.x);
    *reinterpret_cast<unsigned*>(&hb[(long)row * HID + lane * 2]) = pk;
}

// ---------------- launch ----------------

extern "C" void kernel_launch(void* const* d_in, const int* in_sizes, int n_in,
                              void* d_out, int out_size, void* d_ws, size_t ws_size,
                              hipStream_t stream) {
    const float* x      = (const float*)d_in[0];
    const int*   eidx   = (const int*)d_in[1];
    const float* in_W   = (const float*)d_in[2];
    const float* in_b   = (const float*)d_in[3];
    const float* conv_W = (const float*)d_in[4];
    const float* conv_b = (const float*)d_in[5];
    const float* ln_g   = (const float*)d_in[6];
    const float* ln_b   = (const float*)d_in[7];
    const float* out_W  = (const float*)d_in[8];
    const float* out_b  = (const float*)d_in[9];

    const int* src = eidx;
    const int* dst = eidx + E_EDGES;

    char* ws = (char*)d_ws;
    size_t off = 0;
    auto alloc = [&](size_t bytes) {
        void* p = ws + off;
        off += (bytes + 1023) & ~(size_t)1023;
        return p;
    };
    int*   deg       = (int*)  alloc((size_t)N_NODES * 4);
    float* dinv      = (float*)alloc((size_t)N_NODES * 4);
    int*   offsets   = (int*)  alloc((size_t)N_NODES * 4);
    int*   cursor    = (int*)  alloc((size_t)N_NODES * 4);
    int*   blockSums = (int*)  alloc((size_t)NB_SCAN * 4);
    int2*  es        = (int2*) alloc((size_t)E_EDGES * 8);
    float* h         = (float*)alloc((size_t)N_NODES * HID * 4);
    short* hb        = (short*)alloc((size_t)N_NODES * HID * 2);
    short* xwb       = (short*)alloc((size_t)N_NODES * HID * 2);
    short* in_WT     = (short*)alloc((size_t)IN_DIM * HID * 2);
    short* conv_WT   = (short*)alloc((size_t)LAYERS * HID * HID * 2);
    short* out_WT    = (short*)alloc((size_t)HID * OUT_DIM * 2);

    hipMemsetAsync(deg, 0, (size_t)N_NODES * 4, stream);
    deg_kernel<<<(E_EDGES + 255) / 256, 256, 0, stream>>>(dst, deg);
    dinv_kernel<<<(N_NODES + 255) / 256, 256, 0, stream>>>(deg, dinv);

    // CSR build
    block_sum_kernel<<<NB_SCAN, 256, 0, stream>>>(deg, blockSums);
    scan_blocks_kernel<<<1, 512, 0, stream>>>(blockSums, NB_SCAN);
    scan_final_kernel<<<NB_SCAN, 256, 0, stream>>>(deg, blockSums, offsets, cursor);
    bin_kernel<<<(E_EDGES + 255) / 256, 256, 0, stream>>>(src, dst, dinv, cursor, es);

    // weight cast+transpose
    wt_kernel<IN_DIM, HID><<<(IN_DIM * HID + 255) / 256, 256, 0, stream>>>(in_W, in_WT);
    for (int l = 0; l < LAYERS; l++)
        wt_kernel<HID, HID><<<(HID * HID + 255) / 256, 256, 0, stream>>>(
            conv_W + (size_t)l * HID * HID, conv_WT + (size_t)l * HID * HID);
    wt_kernel<HID, OUT_DIM><<<(HID * OUT_DIM + 255) / 256, 256, 0, stream>>>(out_W, out_WT);

    const int ggrid = (N_NODES + 127) / 128;   // 782

    // h = x @ in_W + in_b   (A = f32 x, converted in-flight)
    mfma_gemm<IN_DIM, HID, false><<<ggrid, 256, 0, stream>>>(
        (const void*)x, in_WT, in_b, h, hb, N_NODES);

    for (int l = 0; l < LAYERS; l++) {
        // xwb = hb @ conv_W   (bf16 output only)
        mfma_gemm<HID, HID, true><<<ggrid, 256, 0, stream>>>(
            (const void*)hb, conv_WT + (size_t)l * HID * HID, nullptr, nullptr, xwb, N_NODES);
        gather_post_kernel<<<(N_NODES + 3) / 4, 256, 0, stream>>>(
            offsets, deg, es, dinv, xwb,
            conv_b + l * HID, ln_g + l * HID, ln_b + l * HID, h, hb);
    }

    mfma_gemm<HID, OUT_DIM, true><<<ggrid, 256, 0, stream>>>(
        (const void*)hb, out_WT, out_b, (float*)d_out, nullptr, N_NODES);
}

// Round 10
// 735.252 us; speedup vs baseline: 12.5998x; 1.0657x over previous
//
#include <hip/hip_runtime.h>
#include <hip/hip_bf16.h>

#define N_NODES 100000
#define E_EDGES 1600000
#define IN_DIM  256
#define HID     128
#define OUT_DIM 64
#define LAYERS  3
#define LN_EPS  1e-5f

typedef __attribute__((ext_vector_type(8)))  short bf16x8;   // 8 bf16 = 4 VGPRs
typedef __attribute__((ext_vector_type(16))) float f32x16;   // MFMA 32x32 accumulator

__device__ inline short f2bf(float f) {              // round-to-nearest-even
    unsigned u = __float_as_uint(f);
    unsigned r = (u + 0x7fffu + ((u >> 16) & 1u)) >> 16;
    return (short)r;
}
__device__ inline float bflo(unsigned u) { return __uint_as_float(u << 16); }
__device__ inline float bfhi(unsigned u) { return __uint_as_float(u & 0xffff0000u); }

// ---------------- degree / dinv ----------------

__global__ __launch_bounds__(256) void deg_kernel(const int* __restrict__ dst, int* __restrict__ deg) {
    int e = blockIdx.x * 256 + threadIdx.x;
    if (e < E_EDGES) atomicAdd(&deg[dst[e]], 1);
}

__global__ __launch_bounds__(256) void dinv_kernel(const int* __restrict__ deg, float* __restrict__ dinv) {
    int i = blockIdx.x * 256 + threadIdx.x;
    if (i < N_NODES) dinv[i] = rsqrtf((float)(deg[i] + 1));  // +1 = self loop
}

// ---------------- CSR build ----------------

#define NB_SCAN ((N_NODES + 255) / 256)   // 391

__global__ __launch_bounds__(256) void block_sum_kernel(const int* __restrict__ deg,
                                                        int* __restrict__ blockSums) {
    __shared__ int s[256];
    int i = blockIdx.x * 256 + threadIdx.x;
    s[threadIdx.x] = (i < N_NODES) ? deg[i] : 0;
    __syncthreads();
#pragma unroll
    for (int o = 128; o; o >>= 1) {
        if (threadIdx.x < o) s[threadIdx.x] += s[threadIdx.x + o];
        __syncthreads();
    }
    if (threadIdx.x == 0) blockSums[blockIdx.x] = s[0];
}

__global__ __launch_bounds__(512) void scan_blocks_kernel(int* __restrict__ blockSums, int nb) {
    __shared__ int s[512];
    int t = threadIdx.x;
    int orig = (t < nb) ? blockSums[t] : 0;
    s[t] = orig;
    __syncthreads();
#pragma unroll
    for (int o = 1; o < 512; o <<= 1) {
        int v = (t >= o) ? s[t - o] : 0;
        __syncthreads();
        s[t] += v;
        __syncthreads();
    }
    if (t < nb) blockSums[t] = s[t] - orig;   // exclusive
}

__global__ __launch_bounds__(256) void scan_final_kernel(const int* __restrict__ deg,
                                                         const int* __restrict__ blockSums,
                                                         int* __restrict__ offsets,
                                                         int* __restrict__ cursor) {
    __shared__ int s[256];
    int i = blockIdx.x * 256 + threadIdx.x;
    int t = threadIdx.x;
    int v = (i < N_NODES) ? deg[i] : 0;
    s[t] = v;
    __syncthreads();
#pragma unroll
    for (int o = 1; o < 256; o <<= 1) {
        int u = (t >= o) ? s[t - o] : 0;
        __syncthreads();
        s[t] += u;
        __syncthreads();
    }
    if (i < N_NODES) {
        int excl = s[t] - v + blockSums[blockIdx.x];
        offsets[i] = excl;
        cursor[i] = excl;
    }
}

__global__ __launch_bounds__(256) void bin_kernel(const int* __restrict__ src,
                                                  const int* __restrict__ dst,
                                                  const float* __restrict__ dinv,
                                                  int* __restrict__ cursor,
                                                  int2* __restrict__ es) {
    int e = blockIdx.x * 256 + threadIdx.x;
    if (e >= E_EDGES) return;
    int s = src[e], d = dst[e];
    int p = atomicAdd(&cursor[d], 1);
    es[p] = make_int2(s, __float_as_int(dinv[s] * dinv[d]));
}

// ---------------- weight transpose+cast: WT[n][k] (bf16) from W[k][n] (f32) ----------------

template<int K, int N>
__global__ __launch_bounds__(256) void wt_kernel(const float* __restrict__ W, short* __restrict__ WT) {
    int idx = blockIdx.x * 256 + threadIdx.x;
    if (idx >= K * N) return;
    int n = idx / K, k = idx % K;
    WT[idx] = f2bf(W[(long)k * N + n]);
}

// ---------------- MFMA bf16 GEMM: C[M,N] = A[M,KT] @ W[KT,N] (+bias) ----------------
// No LDS, no barriers. WT is L2/L3-resident; broadcast-read per fragment.
// Wave owns a 32xN tile. __launch_bounds__(256,3): grid=3 blocks/CU -> 3
// waves/SIMD; VGPR cap ~170 lets the compiler keep a deep load pipe.
// Explicit named double-buffer prefetch (static indices after unroll).
// v_mfma_f32_32x32x16_bf16 C layout: col=lane&31, row=(reg&3)+8*(reg>>2)+4*(lane>>5)

template<int KT, int N, bool ABF>
__global__ __launch_bounds__(256, 3) void mfma_gemm(const void* __restrict__ Av,
                                                    const short* __restrict__ WT,
                                                    const float* __restrict__ bias,
                                                    float* __restrict__ C,
                                                    short* __restrict__ Cb,
                                                    int M) {
    constexpr int NT = N / 32;
    constexpr int KTS = KT / 16;

    const int tid = threadIdx.x;
    const int wv = tid >> 6;
    const int ln = tid & 63;
    const int l31 = ln & 31;
    const int lh = ln >> 5;
    const int row0 = blockIdx.x * 128 + wv * 32;

    int ar = row0 + l31;
    if (ar > M - 1) ar = M - 1;                  // clamp; store is guarded

    const short* abf = (const short*)Av + (long)ar * KT + lh * 8;
    const float* af32 = (const float*)Av + (long)ar * KT + lh * 8;
    const short* bbase[NT];
#pragma unroll
    for (int nt = 0; nt < NT; nt++)
        bbase[nt] = WT + (long)(nt * 32 + l31) * KT + lh * 8;

    f32x16 acc[NT];
#pragma unroll
    for (int nt = 0; nt < NT; nt++)
#pragma unroll
        for (int r = 0; r < 16; r++) acc[nt][r] = 0.f;

    auto loadA = [&](int ks) -> bf16x8 {
        if (ABF) {
            return *(const bf16x8*)(abf + ks * 16);
        } else {
            float4 f0 = *(const float4*)(af32 + ks * 16);
            float4 f1 = *(const float4*)(af32 + ks * 16 + 4);
            bf16x8 t;
            t[0] = f2bf(f0.x); t[1] = f2bf(f0.y); t[2] = f2bf(f0.z); t[3] = f2bf(f0.w);
            t[4] = f2bf(f1.x); t[5] = f2bf(f1.y); t[6] = f2bf(f1.z); t[7] = f2bf(f1.w);
            return t;
        }
    };

    bf16x8 a_cur, a_nxt;
    bf16x8 b_cur[NT], b_nxt[NT];

    a_cur = loadA(0);
#pragma unroll
    for (int nt = 0; nt < NT; nt++) b_cur[nt] = *(const bf16x8*)(bbase[nt]);

#pragma unroll
    for (int ks = 0; ks < KTS; ks++) {
        if (ks + 1 < KTS) {
            a_nxt = loadA(ks + 1);
#pragma unroll
            for (int nt = 0; nt < NT; nt++)
                b_nxt[nt] = *(const bf16x8*)(bbase[nt] + (ks + 1) * 16);
        }
#pragma unroll
        for (int nt = 0; nt < NT; nt++)
            acc[nt] = __builtin_amdgcn_mfma_f32_32x32x16_bf16(a_cur, b_cur[nt], acc[nt], 0, 0, 0);
        if (ks + 1 < KTS) {
            a_cur = a_nxt;
#pragma unroll
            for (int nt = 0; nt < NT; nt++) b_cur[nt] = b_nxt[nt];
        }
    }

    // epilogue
#pragma unroll
    for (int nt = 0; nt < NT; nt++) {
        int col = nt * 32 + l31;
        float bv = bias ? bias[col] : 0.f;
#pragma unroll
        for (int r = 0; r < 16; r++) {
            int row = row0 + (r & 3) + 8 * (r >> 2) + 4 * lh;
            if (row < M) {
                float v = acc[nt][r] + bv;
                if (C)  C[(long)row * N + col] = v;
                if (Cb) Cb[(long)row * N + col] = f2bf(v);
            }
        }
    }
}

// ---------------- fused gather + selfloop + bias + LN + relu + residual ----------------
// one wave per node, 2 features per lane; 8-deep gather unroll for MLP.

__global__ __launch_bounds__(256) void gather_post_kernel(const int* __restrict__ offsets,
                                                          const int* __restrict__ deg,
                                                          const int2* __restrict__ es,
                                                          const float* __restrict__ dinv,
                                                          const short* __restrict__ xwb,
                                                          const float* __restrict__ b,
                                                          const float* __restrict__ g,
                                                          const float* __restrict__ beta,
                                                          float* __restrict__ h,
                                                          short* __restrict__ hb) {
    int wave = threadIdx.x >> 6;
    int lane = threadIdx.x & 63;
    int row = blockIdx.x * 4 + wave;
    if (row >= N_NODES) return;

    const int2* ep = es + offsets[row];
    int dg = deg[row];

    float acc0 = 0.f, acc1 = 0.f;
    int j = 0;
    for (; j + 8 <= dg; j += 8) {
        int2 e0 = ep[j + 0];
        int2 e1 = ep[j + 1];
        int2 e2 = ep[j + 2];
        int2 e3 = ep[j + 3];
        int2 e4 = ep[j + 4];
        int2 e5 = ep[j + 5];
        int2 e6 = ep[j + 6];
        int2 e7 = ep[j + 7];
        unsigned u0 = *(const unsigned*)(&xwb[(long)e0.x * HID + lane * 2]);
        unsigned u1 = *(const unsigned*)(&xwb[(long)e1.x * HID + lane * 2]);
        unsigned u2 = *(const unsigned*)(&xwb[(long)e2.x * HID + lane * 2]);
        unsigned u3 = *(const unsigned*)(&xwb[(long)e3.x * HID + lane * 2]);
        unsigned u4 = *(const unsigned*)(&xwb[(long)e4.x * HID + lane * 2]);
        unsigned u5 = *(const unsigned*)(&xwb[(long)e5.x * HID + lane * 2]);
        unsigned u6 = *(const unsigned*)(&xwb[(long)e6.x * HID + lane * 2]);
        unsigned u7 = *(const unsigned*)(&xwb[(long)e7.x * HID + lane * 2]);
        float w0 = __int_as_float(e0.y), w1 = __int_as_float(e1.y);
        float w2 = __int_as_float(e2.y), w3 = __int_as_float(e3.y);
        float w4 = __int_as_float(e4.y), w5 = __int_as_float(e5.y);
        float w6 = __int_as_float(e6.y), w7 = __int_as_float(e7.y);
        acc0 += bflo(u0) * w0; acc1 += bfhi(u0) * w0;
        acc0 += bflo(u1) * w1; acc1 += bfhi(u1) * w1;
        acc0 += bflo(u2) * w2; acc1 += bfhi(u2) * w2;
        acc0 += bflo(u3) * w3; acc1 += bfhi(u3) * w3;
        acc0 += bflo(u4) * w4; acc1 += bfhi(u4) * w4;
        acc0 += bflo(u5) * w5; acc1 += bfhi(u5) * w5;
        acc0 += bflo(u6) * w6; acc1 += bfhi(u6) * w6;
        acc0 += bflo(u7) * w7; acc1 += bfhi(u7) * w7;
    }
    if (j + 4 <= dg) {
        int2 e0 = ep[j + 0];
        int2 e1 = ep[j + 1];
        int2 e2 = ep[j + 2];
        int2 e3 = ep[j + 3];
        unsigned u0 = *(const unsigned*)(&xwb[(long)e0.x * HID + lane * 2]);
        unsigned u1 = *(const unsigned*)(&xwb[(long)e1.x * HID + lane * 2]);
        unsigned u2 = *(const unsigned*)(&xwb[(long)e2.x * HID + lane * 2]);
        unsigned u3 = *(const unsigned*)(&xwb[(long)e3.x * HID + lane * 2]);
        float w0 = __int_as_float(e0.y), w1 = __int_as_float(e1.y);
        float w2 = __int_as_float(e2.y), w3 = __int_as_float(e3.y);
        acc0 += bflo(u0) * w0; acc1 += bfhi(u0) * w0;
        acc0 += bflo(u1) * w1; acc1 += bfhi(u1) * w1;
        acc0 += bflo(u2) * w2; acc1 += bfhi(u2) * w2;
        acc0 += bflo(u3) * w3; acc1 += bfhi(u3) * w3;
        j += 4;
    }
    for (; j < dg; j++) {
        int2 e0 = ep[j];
        float w0 = __int_as_float(e0.y);
        unsigned u0 = *(const unsigned*)(&xwb[(long)e0.x * HID + lane * 2]);
        acc0 += bflo(u0) * w0; acc1 += bfhi(u0) * w0;
    }

    float di = dinv[row];
    float sw = di * di;
    unsigned ux = *(const unsigned*)(&xwb[(long)row * HID + lane * 2]);
    float2 bv = *reinterpret_cast<const float2*>(&b[lane * 2]);
    float y0 = acc0 + bflo(ux) * sw + bv.x;
    float y1 = acc1 + bfhi(ux) * sw + bv.y;

    float sum = y0 + y1;
#pragma unroll
    for (int o = 32; o; o >>= 1) sum += __shfl_xor(sum, o);
    float mu = sum * (1.0f / HID);

    float d0 = y0 - mu, d1 = y1 - mu;
    float vs = d0 * d0 + d1 * d1;
#pragma unroll
    for (int o = 32; o; o >>= 1) vs += __shfl_xor(vs, o);
    float rstd = rsqrtf(vs * (1.0f / HID) + LN_EPS);

    float2 gv = *reinterpret_cast<const float2*>(&g[lane * 2]);
    float2 bev = *reinterpret_cast<const float2*>(&beta[lane * 2]);
    float r0 = fmaxf(d0 * rstd * gv.x + bev.x, 0.0f);
    float r1 = fmaxf(d1 * rstd * gv.y + bev.y, 0.0f);

    float2* hp = reinterpret_cast<float2*>(&h[(long)row * HID + lane * 2]);
    float2 hv = *hp;
    hv.x += r0;
    hv.y += r1;
    *hp = hv;

    unsigned pk = ((unsigned)(unsigned short)f2bf(hv.y) << 16) |
                  (unsigned)(unsigned short)f2bf(hv.x);
    *reinterpret_cast<unsigned*>(&hb[(long)row * HID + lane * 2]) = pk;
}

// ---------------- launch ----------------

extern "C" void kernel_launch(void* const* d_in, const int* in_sizes, int n_in,
                              void* d_out, int out_size, void* d_ws, size_t ws_size,
                              hipStream_t stream) {
    const float* x      = (const float*)d_in[0];
    const int*   eidx   = (const int*)d_in[1];
    const float* in_W   = (const float*)d_in[2];
    const float* in_b   = (const float*)d_in[3];
    const float* conv_W = (const float*)d_in[4];
    const float* conv_b = (const float*)d_in[5];
    const float* ln_g   = (const float*)d_in[6];
    const float* ln_b   = (const float*)d_in[7];
    const float* out_W  = (const float*)d_in[8];
    const float* out_b  = (const float*)d_in[9];

    const int* src = eidx;
    const int* dst = eidx + E_EDGES;

    char* ws = (char*)d_ws;
    size_t off = 0;
    auto alloc = [&](size_t bytes) {
        void* p = ws + off;
        off += (bytes + 1023) & ~(size_t)1023;
        return p;
    };
    int*   deg       = (int*)  alloc((size_t)N_NODES * 4);
    float* dinv      = (float*)alloc((size_t)N_NODES * 4);
    int*   offsets   = (int*)  alloc((size_t)N_NODES * 4);
    int*   cursor    = (int*)  alloc((size_t)N_NODES * 4);
    int*   blockSums = (int*)  alloc((size_t)NB_SCAN * 4);
    int2*  es        = (int2*) alloc((size_t)E_EDGES * 8);
    float* h         = (float*)alloc((size_t)N_NODES * HID * 4);
    short* hb        = (short*)alloc((size_t)N_NODES * HID * 2);
    short* xwb       = (short*)alloc((size_t)N_NODES * HID * 2);
    short* in_WT     = (short*)alloc((size_t)IN_DIM * HID * 2);
    short* conv_WT   = (short*)alloc((size_t)LAYERS * HID * HID * 2);
    short* out_WT    = (short*)alloc((size_t)HID * OUT_DIM * 2);

    hipMemsetAsync(deg, 0, (size_t)N_NODES * 4, stream);
    deg_kernel<<<(E_EDGES + 255) / 256, 256, 0, stream>>>(dst, deg);
    dinv_kernel<<<(N_NODES + 255) / 256, 256, 0, stream>>>(deg, dinv);

    // CSR build
    block_sum_kernel<<<NB_SCAN, 256, 0, stream>>>(deg, blockSums);
    scan_blocks_kernel<<<1, 512, 0, stream>>>(blockSums, NB_SCAN);
    scan_final_kernel<<<NB_SCAN, 256, 0, stream>>>(deg, blockSums, offsets, cursor);
    bin_kernel<<<(E_EDGES + 255) / 256, 256, 0, stream>>>(src, dst, dinv, cursor, es);

    // weight cast+transpose
    wt_kernel<IN_DIM, HID><<<(IN_DIM * HID + 255) / 256, 256, 0, stream>>>(in_W, in_WT);
    for (int l = 0; l < LAYERS; l++)
        wt_kernel<HID, HID><<<(HID * HID + 255) / 256, 256, 0, stream>>>(
            conv_W + (size_t)l * HID * HID, conv_WT + (size_t)l * HID * HID);
    wt_kernel<HID, OUT_DIM><<<(HID * OUT_DIM + 255) / 256, 256, 0, stream>>>(out_W, out_WT);

    const int ggrid = (N_NODES + 127) / 128;   // 782

    // h = x @ in_W + in_b   (A = f32 x, converted in-flight)
    mfma_gemm<IN_DIM, HID, false><<<ggrid, 256, 0, stream>>>(
        (const void*)x, in_WT, in_b, h, hb, N_NODES);

    for (int l = 0; l < LAYERS; l++) {
        // xwb = hb @ conv_W   (bf16 output only)
        mfma_gemm<HID, HID, true><<<ggrid, 256, 0, stream>>>(
            (const void*)hb, conv_WT + (size_t)l * HID * HID, nullptr, nullptr, xwb, N_NODES);
        gather_post_kernel<<<(N_NODES + 3) / 4, 256, 0, stream>>>(
            offsets, deg, es, dinv, xwb,
            conv_b + l * HID, ln_g + l * HID, ln_b + l * HID, h, hb);
    }

    mfma_gemm<HID, OUT_DIM, true><<<ggrid, 256, 0, stream>>>(
        (const void*)hb, out_WT, out_b, (float*)d_out, nullptr, N_NODES);
}